// Round 8
// baseline (41891.220 us; speedup 1.0000x reference)
//
#include <hip/hip_runtime.h>
#include <stdint.h>

// ---------------------------------------------------------------------------
// Tacotron2-style decoder, 400 sequential steps. R11: 2-gbar schedule.
//   R10 post-mortem: conflict fix (2.2e8->5.2e7) + A1-overlap both null ->
//   floor is the number of serial phases/sync-points, not conflicts/slack.
//   R11: phase B deleted:
//   (1) q computed block-locally in C' (ah[b] . qWT, k/8-interleaved bf16);
//       QP buffer gone.
//   (2) A-pack deleted: A1 live-gathers ac/dh f32 (visible since gbar_b of
//       step t-1 -- safe); x fragments prepacked at INIT for all 400 steps
//       (X2F, static cached). ABA/ABD gone.
//   (3) dec_proj distributed: 8 blocks/batch x 10-11 mel rows, inputs staged
//       once per block in LDS.
//   (4) A2 dec-ctx loads issued before att reduce8 (latency hidden).
// Schedule/step: [A1 live partial GEMMs] gbar [A2 ctx+cells+conv] gbar
//   [C': q + proj(t-1) + energies] sibbar [D softmax+ctx] -> loop.
//   2 gbars + 1 sibbar (was 3 + 1).
// ---------------------------------------------------------------------------

#define NB  32
#define TI  512
#define ED  576
#define TO  400
#define NM  80
#define PR  256
#define AR  1024
#define DR  1024
#define AD  128
#define NFl 32
#define KSz 31
#define KA  1856      // 832 (x,ctx) + 1024 (h=c)
#define KD  2624      // 1600 (ac,ctx) + 1024 (dh)
#define NKT_A 58      // KA/32
#define NKT_D 82      // KD/32
#define REL_IDX 320
#define MF_OFF  512   // sibling-barrier flag slots in FLAGS

// dynamic LDS layout (floats within scr)
//   A2:  reduce8 SoA [0..3639], sG [0..511], sAWI [0..281]
//   C':  sACrow [0..1023], sIN2 [1024..2623], eP [2624..3135]
//   D:   spS [0..575], red [576..583]
//   [3640..4663] sCwB conv out (A2 -> C'), [4664..4791] sACc, [4792..4919] sDCc
//   [4920..5047] sQ
#define SCR_CWB 3640
#define SCR_ACC 4664
#define SCR_DCC 4792
#define SCR_SQ  4920
#define LDS_WA_BYTES (NKT_A*512*2)                    // 59392
#define LDS_WD_BYTES (NKT_D*512*2)                    // 83968
#define LDS_SCR_FLOATS 5048
#define LDS_TOTAL (LDS_WA_BYTES + LDS_WD_BYTES + LDS_SCR_FLOATS*4)  // 163552

typedef __attribute__((ext_vector_type(8))) short bf8_t;
typedef __attribute__((ext_vector_type(4))) float f4_t;
typedef unsigned long long ull;

__device__ __forceinline__ short f2bf(float f){
  union { float f; unsigned u; } v; v.f = f;
  unsigned r = v.u + 0x7fffu + ((v.u >> 16) & 1u);
  return (short)(r >> 16);
}
__device__ __forceinline__ float bf2f(short s){
  union { unsigned u; float f; } v; v.u = ((unsigned)(unsigned short)s) << 16; return v.f;
}
__device__ __forceinline__ float sigm(float x){ return 1.f / (1.f + __expf(-x)); }

__device__ __forceinline__ f4_t MFMA(bf8_t a, bf8_t b, f4_t c){
  return __builtin_amdgcn_mfma_f32_16x16x32_bf16(a, b, c, 0, 0, 0);
}

// ---- coherent (agent-scope relaxed) accessors
__device__ __forceinline__ float cld(const float* p){
  return __hip_atomic_load(p, __ATOMIC_RELAXED, __HIP_MEMORY_SCOPE_AGENT);
}
__device__ __forceinline__ void cst(float* p, float v){
  __hip_atomic_store(p, v, __ATOMIC_RELAXED, __HIP_MEMORY_SCOPE_AGENT);
}
__device__ __forceinline__ ull cld8(const void* p){
  return __hip_atomic_load((const ull*)p, __ATOMIC_RELAXED, __HIP_MEMORY_SCOPE_AGENT);
}

__device__ __forceinline__ bf8_t packrow_coh(const float* p){ // coherent source
  union { ull q; float f[2]; } u0, u1, u2, u3;
  u0.q = cld8(p); u1.q = cld8(p + 2); u2.q = cld8(p + 4); u3.q = cld8(p + 6);
  bf8_t r;
  r[0]=f2bf(u0.f[0]); r[1]=f2bf(u0.f[1]);
  r[2]=f2bf(u1.f[0]); r[3]=f2bf(u1.f[1]);
  r[4]=f2bf(u2.f[0]); r[5]=f2bf(u2.f[1]);
  r[6]=f2bf(u3.f[0]); r[7]=f2bf(u3.f[1]);
  return r;
}

struct Par {
  const float *X2, *PMEM;
  const short *WA, *WD, *WLOC, *MEMBT, *PJW, *X2F, *QWP;
  const float *BSA, *BSD;
  const float *convW, *convb, *vW;
  const float *projb, *gateb;
  const int *mlen;
  float *AC, *DH, *CTX, *AW, *AWC, *EN;
  float *out_mel, *out_gate, *out_align;
  unsigned *FLAGS;
};

// ---- live fragment gathers (f32 coherent sources) --------------------------
__device__ __forceinline__ void ldAH(const Par& p, int ks, int lane, bf8_t& a0, bf8_t& a1){
  const int kb = ks*32 + ((lane >> 4) << 3) - (PR + ED);       // ah part of att K
  a0 = packrow_coh(p.AC + (size_t)(lane & 15)*AR + kb);
  a1 = packrow_coh(p.AC + (size_t)(16 + (lane & 15))*AR + kb);
}
__device__ __forceinline__ void ldDC(const Par& p, int ks, int lane, bf8_t& a0, bf8_t& a1){
  const int kb = ks*32 + ((lane >> 4) << 3);                   // ac part of dec K
  a0 = packrow_coh(p.AC + (size_t)(lane & 15)*AR + kb);
  a1 = packrow_coh(p.AC + (size_t)(16 + (lane & 15))*AR + kb);
}
__device__ __forceinline__ void ldDHf(const Par& p, int ks, int lane, bf8_t& a0, bf8_t& a1){
  const int kb = ks*32 + ((lane >> 4) << 3) - (AR + ED);       // dh part of dec K
  a0 = packrow_coh(p.DH + (size_t)(lane & 15)*DR + kb);
  a1 = packrow_coh(p.DH + (size_t)(16 + (lane & 15))*DR + kb);
}
// ctx fragment: sub = PR (att) or AR (dec); parity cpar
__device__ __forceinline__ void ldCT(const Par& p, int cpar, int ks, int sub, int lane,
                                     bf8_t& a0, bf8_t& a1){
  const int kb = ks*32 + ((lane >> 4) << 3) - sub;
  a0 = packrow_coh(p.CTX + (size_t)cpar*NB*ED + (size_t)(lane & 15)*ED + kb);
  a1 = packrow_coh(p.CTX + (size_t)cpar*NB*ED + (size_t)(16 + (lane & 15))*ED + kb);
}
#define WFR(s, ks) (*((const bf8_t*)(s) + (ks)*64 + lane))

// ---- centralized grid barrier: block0 gathers, single release flag ---------
__device__ __forceinline__ void gbar(unsigned* flags, unsigned tgt){
  __syncthreads();
  if (threadIdx.x == 0)
    __hip_atomic_store(&flags[blockIdx.x], tgt, __ATOMIC_RELAXED, __HIP_MEMORY_SCOPE_AGENT);
  if (blockIdx.x == 0){
    if (threadIdx.x < 256){
      while (__hip_atomic_load(&flags[threadIdx.x], __ATOMIC_RELAXED, __HIP_MEMORY_SCOPE_AGENT) < tgt) {}
    }
    __syncthreads();
    if (threadIdx.x == 0)
      __hip_atomic_store(&flags[REL_IDX], tgt, __ATOMIC_RELAXED, __HIP_MEMORY_SCOPE_AGENT);
  }
  if (threadIdx.x == 0){
    while (__hip_atomic_load(&flags[REL_IDX], __ATOMIC_RELAXED, __HIP_MEMORY_SCOPE_AGENT) < tgt) {}
  }
  __syncthreads();
}

// ---- 8-sibling barrier: blocks (b*8 .. b*8+7) only -------------------------
__device__ __forceinline__ void sibbar(unsigned* mf, int bid, int tid, unsigned tgt){
  __syncthreads();
  if (tid == 0)
    __hip_atomic_store(&mf[bid], tgt, __ATOMIC_RELAXED, __HIP_MEMORY_SCOPE_AGENT);
  const int g = (bid >> 3) << 3;
  if (tid < 8){
    while (__hip_atomic_load(&mf[g + tid], __ATOMIC_RELAXED, __HIP_MEMORY_SCOPE_AGENT) < tgt) {}
  }
  __syncthreads();
}

// ---- 8-wave accumulator reduce -> wave 0. SoA (65-stride, conflict-free) ---
__device__ __forceinline__ void reduce8(float* scr, f4_t& a0, f4_t& a1, int lane, int wv){
  if (wv > 0){
    float* base = scr + (size_t)(wv - 1)*520;
    #pragma unroll
    for (int e = 0; e < 4; ++e) base[e*65 + lane] = a0[e];
    #pragma unroll
    for (int e = 0; e < 4; ++e) base[(4 + e)*65 + lane] = a1[e];
  }
  __syncthreads();
  if (wv == 0){
    #pragma unroll
    for (int w = 0; w < 7; ++w){
      const float* base = scr + (size_t)w*520;
      #pragma unroll
      for (int e = 0; e < 4; ++e) a0[e] += base[e*65 + lane];
      #pragma unroll
      for (int e = 0; e < 4; ++e) a1[e] += base[(4 + e)*65 + lane];
    }
  }
  __syncthreads();
}

// ---- distributed mel/gate projection for step tprev ------------------------
// block (b, r8): outputs o in [r8*10, r8*10+10) (+1 extra for r8==7).
// sIN2 = [DH[b](1024) | CTX[tprev&1][b](576)] staged in LDS.
__device__ void proj_dist(const Par& p, int b, int r8, int tprev,
                          int tid, int lane, int wv, float* sIN2){
  sIN2[tid]        = cld(&p.DH[(size_t)b*DR + tid]);
  sIN2[512 + tid]  = cld(&p.DH[(size_t)b*DR + 512 + tid]);
  const float* ctxg = p.CTX + (size_t)(tprev & 1)*NB*ED + b*ED;
  sIN2[1024 + tid] = cld(ctxg + tid);
  if (tid < 64) sIN2[1536 + tid] = cld(ctxg + 512 + tid);
  __syncthreads();
  const int no = (r8 == 7) ? 11 : 10, o0 = r8*10;
  for (int oi = wv; oi < no; oi += 8){
    const int o = o0 + oi;
    const short* wr = p.PJW + (size_t)o*2048;
    float s = 0.f;
    #pragma unroll
    for (int i2 = 0; i2 < 25; ++i2)
      s += sIN2[lane + 64*i2] * bf2f(wr[lane + 64*i2]);
    #pragma unroll
    for (int d = 32; d > 0; d >>= 1) s += __shfl_down(s, d);
    if (lane == 0){
      if (o < 80) p.out_mel[((size_t)b*NM + o)*TO + tprev] = s + p.projb[o];
      else        p.out_gate[(size_t)b*TO + tprev] = s + p.gateb[0];
    }
  }
  __syncthreads();
}

// ============================ persistent kernel =============================
__global__ __launch_bounds__(512) void k_loop(Par p){
  const int bid = blockIdx.x, tid = threadIdx.x;
  const int lane = tid & 63, wv = tid >> 6;

  extern __shared__ char dsm[];
  short* sWA = (short*)dsm;
  short* sWD = (short*)(dsm + LDS_WA_BYTES);
  float* scr = (float*)(dsm + LDS_WA_BYTES + LDS_WD_BYTES);
  float* sACc = scr + SCR_ACC;
  float* sDCc = scr + SCR_DCC;
  unsigned* mf = p.FLAGS + MF_OFF;

  // ---- one-time: weights -> LDS; cell-state init ---------------------------
  {
    if (tid < 128){ sACc[tid] = 0.f; sDCc[tid] = 0.f; }
    const bf8_t* gwa = (const bf8_t*)(p.WA + (size_t)bid*NKT_A*512);
    bf8_t* lwa = (bf8_t*)sWA;
    for (int i = tid; i < NKT_A*64; i += 512) lwa[i] = gwa[i];
    const bf8_t* gwd = (const bf8_t*)(p.WD + (size_t)bid*NKT_D*512);
    bf8_t* lwd = (bf8_t*)sWD;
    for (int i = tid; i < NKT_D*64; i += 512) lwd[i] = gwd[i];
    __syncthreads();
  }

  for (int t = 0; t < TO; ++t){
    const int wp = t & 1, rp = wp ^ 1;
    const unsigned base = (unsigned)(t * 2);

    f4_t aA0 = (f4_t){0.f,0.f,0.f,0.f}, aA1 = (f4_t){0.f,0.f,0.f,0.f};
    f4_t aD0 = (f4_t){0.f,0.f,0.f,0.f}, aD1 = (f4_t){0.f,0.f,0.f,0.f};

    // ------- A1: live partial GEMMs (reads only state visible since
    //         gbar_b(t-1): AC(t-1), DH(t-2), static X2F) -------------------
    {
      { // att: x tile (prepacked static) + 4 ah tiles
        const bf8_t* xf = (const bf8_t*)p.X2F + ((size_t)t*8 + wv)*128;
        const bf8_t x0 = xf[lane];
        const bf8_t x1 = xf[64 + lane];
        const int ab = (wv < 2) ? (wv + 32) : (wv + 24);
        bf8_t h00,h01,h10,h11,h20,h21,h30,h31;
        ldAH(p, ab +  0, lane, h00, h01);
        ldAH(p, ab +  8, lane, h10, h11);
        ldAH(p, ab + 16, lane, h20, h21);
        ldAH(p, ab + 24, lane, h30, h31);
        aA0 = MFMA(x0, WFR(sWA, wv), aA0);
        aA1 = MFMA(x1, WFR(sWA, wv), aA1);
        aA0 = MFMA(h00, WFR(sWA, ab +  0), aA0);
        aA1 = MFMA(h01, WFR(sWA, ab +  0), aA1);
        aA0 = MFMA(h10, WFR(sWA, ab +  8), aA0);
        aA1 = MFMA(h11, WFR(sWA, ab +  8), aA1);
        aA0 = MFMA(h20, WFR(sWA, ab + 16), aA0);
        aA1 = MFMA(h21, WFR(sWA, ab + 16), aA1);
        aA0 = MFMA(h30, WFR(sWA, ab + 24), aA0);
        aA1 = MFMA(h31, WFR(sWA, ab + 24), aA1);
      }
      { // dec: 4 ac tiles
        bf8_t c00,c01,c10,c11,c20,c21,c30,c31;
        ldDC(p, wv +  0, lane, c00, c01);
        ldDC(p, wv +  8, lane, c10, c11);
        ldDC(p, wv + 16, lane, c20, c21);
        ldDC(p, wv + 24, lane, c30, c31);
        aD0 = MFMA(c00, WFR(sWD, wv +  0), aD0);
        aD1 = MFMA(c01, WFR(sWD, wv +  0), aD1);
        aD0 = MFMA(c10, WFR(sWD, wv +  8), aD0);
        aD1 = MFMA(c11, WFR(sWD, wv +  8), aD1);
        aD0 = MFMA(c20, WFR(sWD, wv + 16), aD0);
        aD1 = MFMA(c21, WFR(sWD, wv + 16), aD1);
        aD0 = MFMA(c30, WFR(sWD, wv + 24), aD0);
        aD1 = MFMA(c31, WFR(sWD, wv + 24), aD1);
      }
      { // dec: 4 dh tiles
        const int db = (wv < 2) ? (wv + 56) : (wv + 48);
        bf8_t h00,h01,h10,h11,h20,h21,h30,h31;
        ldDHf(p, db +  0, lane, h00, h01);
        ldDHf(p, db +  8, lane, h10, h11);
        ldDHf(p, db + 16, lane, h20, h21);
        ldDHf(p, db + 24, lane, h30, h31);
        aD0 = MFMA(h00, WFR(sWD, db +  0), aD0);
        aD1 = MFMA(h01, WFR(sWD, db +  0), aD1);
        aD0 = MFMA(h10, WFR(sWD, db +  8), aD0);
        aD1 = MFMA(h11, WFR(sWD, db +  8), aD1);
        aD0 = MFMA(h20, WFR(sWD, db + 16), aD0);
        aD1 = MFMA(h21, WFR(sWD, db + 16), aD1);
        aD0 = MFMA(h30, WFR(sWD, db + 24), aD0);
        aD1 = MFMA(h31, WFR(sWD, db + 24), aD1);
      }
    }
    gbar(p.FLAGS, base + 1);

    // ------- A2: ctx tiles + cells + conv ----------------------------------
    {
      // hoist conv input loads (coherent) to phase top
      const int bb = bid >> 3, tc = bid & 7, t0 = tc*64;
      float cva = 0.f, cvw = 0.f;
      if (tid < 94){
        const int g = t0 - 15 + tid;
        if (g >= 0 && g < TI){
          cva = cld(&p.AW [(size_t)rp*NB*TI + bb*TI + g]);
          cvw = cld(&p.AWC[(size_t)rp*NB*TI + bb*TI + g]);
        }
      }
      // att ctx tiles (2-3 per wave)
      {
        bf8_t c00,c01,c10,c11,c20,c21;
        const bool c_ok = (wv < 2);
        ldCT(p, rp, wv +  8, PR, lane, c00, c01);
        ldCT(p, rp, wv + 16, PR, lane, c10, c11);
        if (c_ok) ldCT(p, rp, wv + 24, PR, lane, c20, c21);
        aA0 = MFMA(c00, WFR(sWA, wv +  8), aA0);
        aA1 = MFMA(c01, WFR(sWA, wv +  8), aA1);
        aA0 = MFMA(c10, WFR(sWA, wv + 16), aA0);
        aA1 = MFMA(c11, WFR(sWA, wv + 16), aA1);
        if (c_ok){
          aA0 = MFMA(c20, WFR(sWA, wv + 24), aA0);
          aA1 = MFMA(c21, WFR(sWA, wv + 24), aA1);
        }
      }
      // dec ctx tiles: ISSUE loads now (consumed after att reduce/cell)
      bf8_t d00,d01,d10,d11,d20,d21;
      const bool dc_ok = (wv < 2);
      ldCT(p, rp, wv + 32, AR, lane, d00, d01);
      ldCT(p, rp, wv + 40, AR, lane, d10, d11);
      if (dc_ok) ldCT(p, rp, wv + 48, AR, lane, d20, d21);

      reduce8(scr, aA0, aA1, lane, wv);
      float* sG = scr;
      if (wv == 0){
        const int col = lane & 15, rb2 = (lane >> 4) << 2;
        const int jp = (col & 3)*1024 + bid*4 + (col >> 2);
        const float bs = p.BSA[jp];
        #pragma unroll
        for (int r = 0; r < 4; ++r){
          sG[(rb2 + r)*16 + col]      = aA0[r] + bs;
          sG[(16 + rb2 + r)*16 + col] = aA1[r] + bs;
        }
      }
      __syncthreads();
      if (tid < 128){                        // att cell (h := c)
        const int b = tid >> 2, ul = tid & 3;
        const float gi = sG[b*16 + ul*4 + 0];
        const float gf = sG[b*16 + ul*4 + 1];
        const float gg = sG[b*16 + ul*4 + 2];
        const float c  = sigm(gf) * sACc[tid] + sigm(gi) * tanhf(gg);
        sACc[tid] = c;
        cst(&p.AC[(size_t)b*AR + bid*4 + ul], c);
      }
      __syncthreads();
      // dec ctx MFMAs + reduce + cell (cell skipped at t==0)
      aD0 = MFMA(d00, WFR(sWD, wv + 32), aD0);
      aD1 = MFMA(d01, WFR(sWD, wv + 32), aD1);
      aD0 = MFMA(d10, WFR(sWD, wv + 40), aD0);
      aD1 = MFMA(d11, WFR(sWD, wv + 40), aD1);
      if (dc_ok){
        aD0 = MFMA(d20, WFR(sWD, wv + 48), aD0);
        aD1 = MFMA(d21, WFR(sWD, wv + 48), aD1);
      }
      reduce8(scr, aD0, aD1, lane, wv);
      if (wv == 0){
        const int col = lane & 15, rb2 = (lane >> 4) << 2;
        const int jp = (col & 3)*1024 + bid*4 + (col >> 2);
        const float bs = p.BSD[jp];
        #pragma unroll
        for (int r = 0; r < 4; ++r){
          sG[(rb2 + r)*16 + col]      = aD0[r] + bs;
          sG[(16 + rb2 + r)*16 + col] = aD1[r] + bs;
        }
      }
      __syncthreads();
      if (t > 0 && tid < 128){               // dec cell for step t-1
        const int b = tid >> 2, ul = tid & 3;
        const float gi = sG[b*16 + ul*4 + 0];
        const float gf = sG[b*16 + ul*4 + 1];
        const float gg = sG[b*16 + ul*4 + 2];
        const float go = sG[b*16 + ul*4 + 3];
        const float c  = sigm(gf) * sDCc[tid] + sigm(gi) * tanhf(gg);
        sDCc[tid] = c;
        cst(&p.DH[(size_t)b*DR + bid*4 + ul], sigm(go) * tanhf(c));
      }
      __syncthreads();
      // conv -> sCwB (persists to C')
      float* sAWI = scr;                     // 282 floats (region now dead)
      short* sCwB = (short*)(scr + SCR_CWB); // [64][32] bf16
      if (tid < 94){ sAWI[3*tid] = cva; sAWI[3*tid + 1] = cvw; }
      __syncthreads();
      {
        const int wvu = __builtin_amdgcn_readfirstlane(wv);
        const int f0 = wvu * 4;
        float ac4[4];
        #pragma unroll
        for (int ff = 0; ff < 4; ++ff) ac4[ff] = p.convb[f0 + ff];
        for (int k = 0; k < KSz; ++k){
          const float av  = sAWI[3*(lane + k)];
          const float wcv = sAWI[3*(lane + k) + 1];
          #pragma unroll
          for (int ff = 0; ff < 4; ++ff){
            ac4[ff] += av  * p.convW[((f0+ff)*2 + 0)*KSz + k]
                     + wcv * p.convW[((f0+ff)*2 + 1)*KSz + k];
          }
        }
        #pragma unroll
        for (int ff = 0; ff < 4; ++ff) sCwB[lane*32 + f0 + ff] = f2bf(ac4[ff]);
      }
    }
    gbar(p.FLAGS, base + 2);

    // ------- C': q-local + proj(t-1) + energies -----------------------------
    {
      const int b = bid >> 3, r8 = bid & 7, t0 = r8*64;
      float* sACrow = scr;                   // 1024
      float* sIN2   = scr + 1024;            // 1600
      float* eP     = scr + 2624;            // 512
      float* sQ     = scr + SCR_SQ;          // 128
      sACrow[tid]       = cld(&p.AC[(size_t)b*AR + tid]);
      sACrow[512 + tid] = cld(&p.AC[(size_t)b*AR + 512 + tid]);
      __syncthreads();
      { // q[b][d] = ah[b] . qW[d]  (4 lanes per dim, k-quarters)
        const int d = wv*16 + (lane & 15), qq = lane >> 4;
        float acc = 0.f;
        const short* qwp = p.QWP + (size_t)qq*32*1024 + d*8;
        #pragma unroll
        for (int i = 0; i < 32; ++i){
          const bf8_t w8 = *(const bf8_t*)(qwp + i*1024);
          const float* av = sACrow + qq*256 + i*8;
          acc += av[0]*bf2f(w8[0]) + av[1]*bf2f(w8[1]) + av[2]*bf2f(w8[2]) + av[3]*bf2f(w8[3])
               + av[4]*bf2f(w8[4]) + av[5]*bf2f(w8[5]) + av[6]*bf2f(w8[6]) + av[7]*bf2f(w8[7]);
        }
        acc += __shfl_down(acc, 32);
        acc += __shfl_down(acc, 16);
        if (lane < 16) sQ[wv*16 + lane] = acc;
      }
      __syncthreads();
      if (t > 0) proj_dist(p, b, r8, t - 1, tid, lane, wv, sIN2);
      // energies: per-wave 16-d slice; loc-proj MFMA recomputed from sCwB
      short* sCwB = (short*)(scr + SCR_CWB);
      const int g = lane >> 4, li = lane & 15;
      const int d2 = wv*16 + li;
      const float vw = p.vW[d2];
      const float qd = sQ[d2];
      const bf8_t bfr = *(const bf8_t*)(p.WLOC + (size_t)(wv*64 + lane)*8);
      #pragma unroll
      for (int mt = 0; mt < 4; ++mt){
        const bf8_t afr = *(const bf8_t*)(sCwB + (mt*16 + li)*32 + (g << 3));
        f4_t c = (f4_t){0.f,0.f,0.f,0.f};
        c = MFMA(afr, bfr, c);
        #pragma unroll
        for (int r = 0; r < 4; ++r){
          const int tg = t0 + mt*16 + g*4 + r;
          const float val = c[r] + p.PMEM[((size_t)b*TI + tg)*AD + d2];
          float v = vw * tanhf(qd + val);
          v += __shfl_xor(v, 1);
          v += __shfl_xor(v, 2);
          v += __shfl_xor(v, 4);
          v += __shfl_xor(v, 8);
          if (li == 0) eP[wv*64 + mt*16 + g*4 + r] = v;
        }
      }
      __syncthreads();
      if (tid < 64){
        float e = eP[tid];
        #pragma unroll
        for (int w2 = 1; w2 < 8; ++w2) e += eP[w2*64 + tid];
        const int tg = t0 + tid;
        cst(&p.EN[b*TI + tg], (tg < p.mlen[b]) ? e : -1e30f);
      }
    }
    sibbar(mf, bid, tid, (unsigned)(t + 1));

    // ------- D: softmax (shfl) + context; sp SoA stride-72 ------------------
    {
      const int b = bid >> 3, ec = bid & 7;
      float* spS = scr;                          // 8*72 = 576
      float* red = scr + 576;                    // 8
      const float e = cld(&p.EN[b*TI + tid]);
      float m = e;
      #pragma unroll
      for (int d = 32; d > 0; d >>= 1) m = fmaxf(m, __shfl_xor(m, d));
      if (lane == 0) red[wv] = m;
      __syncthreads();
      const float M = fmaxf(fmaxf(fmaxf(red[0], red[1]), fmaxf(red[2], red[3])),
                            fmaxf(fmaxf(red[4], red[5]), fmaxf(red[6], red[7])));
      const float x = __expf(e - M);
      float z = x;
      #pragma unroll
      for (int d = 32; d > 0; d >>= 1) z += __shfl_xor(z, d);
      __syncthreads();
      if (lane == 0) red[wv] = z;
      __syncthreads();
      const float Z = red[0]+red[1]+red[2]+red[3]+red[4]+red[5]+red[6]+red[7];
      const float pv = x / Z;
      spS[(tid & 7)*72 + (tid >> 3)] = pv;
      if (ec == 0){
        cst(&p.AW [(size_t)wp*NB*TI + b*TI + tid], pv);
        cst(&p.AWC[(size_t)wp*NB*TI + b*TI + tid],
            cld(&p.AWC[(size_t)rp*NB*TI + b*TI + tid]) + pv);
        p.out_align[((size_t)b*TO + t)*TI + tid] = pv;
      }
      __syncthreads();
      #pragma unroll
      for (int ii = 0; ii < 9; ++ii){
        const int e2 = ec*72 + wv*9 + ii;
        const short* row = p.MEMBT + ((size_t)b*ED + e2)*TI;
        const bf8_t w8 = *(const bf8_t*)(row + lane*8);
        float a2 = spS[0*72+lane]*bf2f(w8[0]) + spS[1*72+lane]*bf2f(w8[1])
                 + spS[2*72+lane]*bf2f(w8[2]) + spS[3*72+lane]*bf2f(w8[3])
                 + spS[4*72+lane]*bf2f(w8[4]) + spS[5*72+lane]*bf2f(w8[5])
                 + spS[6*72+lane]*bf2f(w8[6]) + spS[7*72+lane]*bf2f(w8[7]);
        #pragma unroll
        for (int d = 32; d > 0; d >>= 1) a2 += __shfl_down(a2, d);
        if (lane == 0)
          cst(&p.CTX[(size_t)wp*NB*ED + b*ED + e2], a2);
      }
    }
    // no trailing gbar: A1(t+1) reads only AC(t)/DH(t-1)/X2F (visible
    // since gbar base+2); CTX(t)/AW(t) first read in A2(t+1) after gbar.
  }

  // ---- tail: dec-gates+cell(TO-1), then distributed proj(TO-1) -------------
  gbar(p.FLAGS, (unsigned)(2*TO + 1));
  {
    const int cpar = (TO - 1) & 1;
    f4_t d0v = (f4_t){0.f,0.f,0.f,0.f}, d1v = (f4_t){0.f,0.f,0.f,0.f};
    { // ac tiles
      bf8_t c00,c01,c10,c11,c20,c21,c30,c31;
      ldDC(p, wv +  0, lane, c00, c01);
      ldDC(p, wv +  8, lane, c10, c11);
      ldDC(p, wv + 16, lane, c20, c21);
      ldDC(p, wv + 24, lane, c30, c31);
      d0v = MFMA(c00, WFR(sWD, wv +  0), d0v);
      d1v = MFMA(c01, WFR(sWD, wv +  0), d1v);
      d0v = MFMA(c10, WFR(sWD, wv +  8), d0v);
      d1v = MFMA(c11, WFR(sWD, wv +  8), d1v);
      d0v = MFMA(c20, WFR(sWD, wv + 16), d0v);
      d1v = MFMA(c21, WFR(sWD, wv + 16), d1v);
      d0v = MFMA(c30, WFR(sWD, wv + 24), d0v);
      d1v = MFMA(c31, WFR(sWD, wv + 24), d1v);
    }
    { // dh tiles
      const int db = (wv < 2) ? (wv + 56) : (wv + 48);
      bf8_t h00,h01,h10,h11,h20,h21,h30,h31;
      ldDHf(p, db +  0, lane, h00, h01);
      ldDHf(p, db +  8, lane, h10, h11);
      ldDHf(p, db + 16, lane, h20, h21);
      ldDHf(p, db + 24, lane, h30, h31);
      d0v = MFMA(h00, WFR(sWD, db +  0), d0v);
      d1v = MFMA(h01, WFR(sWD, db +  0), d1v);
      d0v = MFMA(h10, WFR(sWD, db +  8), d0v);
      d1v = MFMA(h11, WFR(sWD, db +  8), d1v);
      d0v = MFMA(h20, WFR(sWD, db + 16), d0v);
      d1v = MFMA(h21, WFR(sWD, db + 16), d1v);
      d0v = MFMA(h30, WFR(sWD, db + 24), d0v);
      d1v = MFMA(h31, WFR(sWD, db + 24), d1v);
    }
    { // ctx tiles
      bf8_t e00,e01,e10,e11,e20,e21;
      const bool c_ok = (wv < 2);
      ldCT(p, cpar, wv + 32, AR, lane, e00, e01);
      ldCT(p, cpar, wv + 40, AR, lane, e10, e11);
      if (c_ok) ldCT(p, cpar, wv + 48, AR, lane, e20, e21);
      d0v = MFMA(e00, WFR(sWD, wv + 32), d0v);
      d1v = MFMA(e01, WFR(sWD, wv + 32), d1v);
      d0v = MFMA(e10, WFR(sWD, wv + 40), d0v);
      d1v = MFMA(e11, WFR(sWD, wv + 40), d1v);
      if (c_ok){
        d0v = MFMA(e20, WFR(sWD, wv + 48), d0v);
        d1v = MFMA(e21, WFR(sWD, wv + 48), d1v);
      }
    }
    reduce8(scr, d0v, d1v, lane, wv);
    float* sG = scr;
    if (wv == 0){
      const int col = lane & 15, rb2 = (lane >> 4) << 2;
      const int jp = (col & 3)*1024 + bid*4 + (col >> 2);
      const float bs = p.BSD[jp];
      #pragma unroll
      for (int r = 0; r < 4; ++r){
        sG[(rb2 + r)*16 + col]      = d0v[r] + bs;
        sG[(16 + rb2 + r)*16 + col] = d1v[r] + bs;
      }
    }
    __syncthreads();
    if (tid < 128){
      const int b = tid >> 2, ul = tid & 3;
      const float gi = sG[b*16 + ul*4 + 0];
      const float gf = sG[b*16 + ul*4 + 1];
      const float gg = sG[b*16 + ul*4 + 2];
      const float go = sG[b*16 + ul*4 + 3];
      const float c  = sigm(gf) * sDCc[tid] + sigm(gi) * tanhf(gg);
      sDCc[tid] = c;
      cst(&p.DH[(size_t)b*DR + bid*4 + ul], sigm(go) * tanhf(c));
    }
  }
  gbar(p.FLAGS, (unsigned)(2*TO + 2));
  proj_dist(p, bid >> 3, bid & 7, TO - 1, tid, lane, wv, scr + 1024);
}

// ============================ setup kernels =================================
__global__ __launch_bounds__(256) void k_init(float* z, int nz,
                                              float* bsa, const float* a1, const float* a2,
                                              float* bsd, const float* d1, const float* d2){
  const int idx = blockIdx.x*256 + threadIdx.x, st = gridDim.x*256;
  const int NG = 4096;
  for (int i = idx; i < nz; i += st) z[i] = 0.f;
  for (int i = idx; i < NG; i += st){ bsa[i] = a1[i] + a2[i]; bsd[i] = d1[i] + d2[i]; }
}

__global__ __launch_bounds__(256) void k_prenet1(const float* di, const float* W1, float* X1){
  const int t = blockIdx.x, tid = threadIdx.x;
  __shared__ float sdi[NB*NM];
  for (int i = tid; i < NB*NM; i += 256){
    const int b = i / NM, k = i - b*NM;
    sdi[i] = (t == 0) ? 0.f : di[((size_t)b*TO + (t-1))*NM + k];
  }
  __syncthreads();
  float acc[NB];
  #pragma unroll
  for (int b = 0; b < NB; ++b) acc[b] = 0.f;
  const int j = tid;
  for (int k = 0; k < NM; ++k){
    const float w = W1[j*NM + k];
    #pragma unroll
    for (int b = 0; b < NB; ++b) acc[b] += sdi[b*NM + k] * w;
  }
  for (int b = 0; b < NB; ++b)
    X1[((size_t)t*NB + b)*PR + j] = fmaxf(acc[b], 0.f);
}

__global__ __launch_bounds__(256) void k_prenet2(const float* X1, const float* W2, float* X2){
  const int t = blockIdx.x, tid = threadIdx.x;
  __shared__ float sx[NB*PR];
  for (int i = tid; i < NB*PR; i += 256) sx[i] = X1[(size_t)t*NB*PR + i];
  __syncthreads();
  float acc[NB];
  #pragma unroll
  for (int b = 0; b < NB; ++b) acc[b] = 0.f;
  const int j = tid;
  for (int k = 0; k < PR; ++k){
    const float w = W2[j*PR + k];
    #pragma unroll
    for (int b = 0; b < NB; ++b) acc[b] += sx[b*PR + k] * w;
  }
  for (int b = 0; b < NB; ++b)
    X2[((size_t)t*NB + b)*PR + j] = fmaxf(acc[b], 0.f);
}

// X2 -> bf16 MFMA A-fragments for all t: X2F[(t*8+ks)*2 + m][64][8]
__global__ __launch_bounds__(64) void k_x2f(const float* X2, short* xf){
  const int t = blockIdx.x, lane = threadIdx.x;
  for (int ks = 0; ks < 8; ++ks){
    for (int m = 0; m < 2; ++m){
      const int row = m*16 + (lane & 15);
      const int k0 = ks*32 + ((lane >> 4) << 3);
      bf8_t v;
      #pragma unroll
      for (int j = 0; j < 8; ++j)
        v[j] = f2bf(X2[((size_t)t*NB + row)*PR + k0 + j]);
      *(bf8_t*)(xf + (((size_t)t*8 + ks)*2 + m)*512 + lane*8) = v;
    }
  }
}

// qW[128][1024] f32 -> k/8-interleaved bf16: QWP[(k>>3)*1024 + d*8 + (k&7)]
__global__ __launch_bounds__(128) void k_swz_qt(const float* qW, short* dst){
  const int kb = blockIdx.x;                   // 0..127 (k-block of 8)
  const int d  = threadIdx.x;                  // 0..127
  #pragma unroll
  for (int j = 0; j < 8; ++j)
    dst[(size_t)kb*1024 + d*8 + j] = f2bf(qW[(size_t)d*AR + kb*8 + j]);
}

__global__ __launch_bounds__(256) void k_pmem(const float* mem, const float* memW, float* pm){
  const int b = blockIdx.x >> 3, tc = blockIdx.x & 7, tid = threadIdx.x;
  __shared__ float sW[64*AD];
  __shared__ float sM[64*65];
  const int tl = tid >> 2, dq = tid & 3;
  float acc[32];
  #pragma unroll
  for (int i = 0; i < 32; ++i) acc[i] = 0.f;
  for (int kc = 0; kc < 9; ++kc){
    __syncthreads();
    for (int i = tid; i < 64*AD; i += 256){
      const int d = i >> 6, kl = i & 63;
      sW[kl*AD + ((d + kl) & 127)] = memW[(size_t)d*ED + kc*64 + kl];
    }
    for (int i = tid; i < 64*64; i += 256){
      const int tt = i >> 6, kl = i & 63;
      sM[tt*65 + kl] = mem[((size_t)b*TI + tc*64 + tt)*ED + kc*64 + kl];
    }
    __syncthreads();
    for (int kl = 0; kl < 64; ++kl){
      const float mv = sM[tl*65 + kl];
      #pragma unroll
      for (int d2 = 0; d2 < 32; ++d2)
        acc[d2] += mv * sW[kl*AD + ((dq*32 + d2 + kl) & 127)];
    }
  }
  for (int d2 = 0; d2 < 32; ++d2)
    pm[((size_t)b*TI + tc*64 + tl)*AD + dq*32 + d2] = acc[d2];
}

// memory -> bf16 transposed [b][e][t] (coalesced ctx matvec)
__global__ __launch_bounds__(256) void k_membt(const float* mem, short* mt){
  const int b = blockIdx.x / 36, ec = blockIdx.x % 36;
  __shared__ float sT[64*17];
  for (int tc = 0; tc < 8; ++tc){
    __syncthreads();
    for (int i = threadIdx.x; i < 64*16; i += 256){
      const int tt = i >> 4, e = i & 15;
      sT[tt*17 + e] = mem[((size_t)b*TI + tc*64 + tt)*ED + ec*16 + e];
    }
    __syncthreads();
    for (int i = threadIdx.x; i < 16*64; i += 256){
      const int e = i >> 6, tt = i & 63;
      mt[((size_t)b*ED + ec*16 + e)*TI + tc*64 + tt] = f2bf(sT[tt*17 + e]);
    }
  }
}

// weights -> bf16 MFMA B-fragment layout, gate-interleaved columns
__global__ __launch_bounds__(64) void k_swz_gate(const float* Wih, const float* Whh,
                                                 short* dst, int split, int nkt){
  const int bidx = blockIdx.x;
  const int nt = bidx / nkt, kt = bidx - nt*nkt;
  const int lane = threadIdx.x;
  const int nl = lane & 15;
  const int jp = (nl & 3)*1024 + nt*4 + (nl >> 2);
  const int k0 = kt*32 + ((lane >> 4) << 3);
  bf8_t v;
  #pragma unroll
  for (int jj = 0; jj < 8; ++jj){
    const int k = k0 + jj;
    const float f = (k < split) ? Wih[(size_t)jp*split + k]
                                : Whh[(size_t)jp*1024 + (k - split)];
    v[jj] = f2bf(f);
  }
  *(bf8_t*)(dst + (size_t)bidx*512 + lane*8) = v;
}

__global__ __launch_bounds__(64) void k_swz_loc(const float* locW, short* dst){
  const int nt = blockIdx.x;                   // 0..7
  const int lane = threadIdx.x;
  const int d = nt*16 + (lane & 15);
  const int f0 = (lane >> 4) << 3;
  bf8_t v;
  #pragma unroll
  for (int jj = 0; jj < 8; ++jj) v[jj] = f2bf(locW[d*NFl + f0 + jj]);
  *(bf8_t*)(dst + (size_t)(nt*64 + lane)*8) = v;
}

// projW(80x1600) + gateW(1x1600) -> bf16 rows, padded to stride 2048 (zeros)
__global__ __launch_bounds__(256) void k_swz_proj(const float* projW, const float* gateW,
                                                  short* dst){
  const int o = blockIdx.x;                    // 0..80
  const float* src = (o < 80) ? (projW + (size_t)o*1600) : gateW;
  for (int k = threadIdx.x; k < 2048; k += 256)
    dst[(size_t)o*2048 + k] = (k < 1600) ? f2bf(src[k]) : (short)0;
}

// ============================== launch ======================================
extern "C" void kernel_launch(void* const* d_in, const int* in_sizes, int n_in,
                              void* d_out, int out_size, void* d_ws, size_t ws_size,
                              hipStream_t stream){
  const float* mem    = (const float*)d_in[0];
  const float* dec_in = (const float*)d_in[1];
  const float* pW1    = (const float*)d_in[2];
  const float* pW2    = (const float*)d_in[3];
  const float* aWih   = (const float*)d_in[4];
  const float* aWhh   = (const float*)d_in[5];
  const float* aBih   = (const float*)d_in[6];
  const float* aBhh   = (const float*)d_in[7];
  const float* qW     = (const float*)d_in[8];
  const float* memW   = (const float*)d_in[9];
  const float* convW  = (const float*)d_in[10];
  const float* convb  = (const float*)d_in[11];
  const float* locW   = (const float*)d_in[12];
  const float* vW     = (const float*)d_in[13];
  const float* dWih   = (const float*)d_in[14];
  const float* dWhh   = (const float*)d_in[15];
  const float* dBih   = (const float*)d_in[16];
  const float* dBhh   = (const float*)d_in[17];
  const float* projW  = (const float*)d_in[18];
  const float* projb  = (const float*)d_in[19];
  const float* gateW  = (const float*)d_in[20];
  const float* gateb  = (const float*)d_in[21];
  const int*   mlen   = (const int*)d_in[22];
  (void)in_sizes; (void)n_in; (void)out_size; (void)ws_size;

  char* basep = (char*)d_ws;
  size_t off = 0;
  auto carve = [&](size_t bytes) -> char* {
    char* r = basep + off;
    off = (off + bytes + 255) & ~(size_t)255;
    return r;
  };
  const int NG = 4096;
  short* WA    = (short*)carve((size_t)NG*KA*2);
  short* WD    = (short*)carve((size_t)NG*KD*2);
  short* QWP   = (short*)carve((size_t)AD*AR*2);
  short* WLOC  = (short*)carve((size_t)AD*NFl*2);
  short* MEMBT = (short*)carve((size_t)NB*TI*ED*2);
  short* PJW   = (short*)carve((size_t)81*2048*2);
  short* X2F   = (short*)carve((size_t)TO*16*512*2);
  float* X1    = (float*)carve((size_t)TO*NB*PR*4);
  float* X2    = (float*)carve((size_t)TO*NB*PR*4);
  float* PMEM  = (float*)carve((size_t)NB*TI*AD*4);
  float* BSA   = (float*)carve((size_t)NG*4);
  float* BSD   = (float*)carve((size_t)NG*4);
  // ---- zero-span begins here (contiguous through FLAGS) ----
  float* AC    = (float*)carve((size_t)NB*AR*4);
  float* DH    = (float*)carve((size_t)NB*DR*4);
  float* CTX   = (float*)carve((size_t)2*NB*ED*4);
  float* AW    = (float*)carve((size_t)2*NB*TI*4);
  float* AWC   = (float*)carve((size_t)2*NB*TI*4);
  float* EN    = (float*)carve((size_t)NB*TI*4);
  unsigned* FLAGS = (unsigned*)carve(4096);
  const int nz = (int)((((char*)FLAGS + 4096) - (char*)AC) / 4);

  float* out_mel   = (float*)d_out;
  float* out_gate  = out_mel + (size_t)NB*NM*TO;
  float* out_align = out_gate + (size_t)NB*TO;

  k_init   <<<dim3(512), dim3(256), 0, stream>>>(AC, nz, BSA, aBih, aBhh, BSD, dBih, dBhh);
  k_prenet1<<<dim3(TO),  dim3(256), 0, stream>>>(dec_in, pW1, X1);
  k_prenet2<<<dim3(TO),  dim3(256), 0, stream>>>(X1, pW2, X2);
  k_x2f    <<<dim3(TO),  dim3(64),  0, stream>>>(X2, X2F);
  k_pmem   <<<dim3(256), dim3(256), 0, stream>>>(mem, memW, PMEM);
  k_membt  <<<dim3(NB*36), dim3(256), 0, stream>>>(mem, MEMBT);
  k_swz_gate<<<dim3(256*NKT_A), dim3(64), 0, stream>>>(aWih, aWhh, WA, 832, NKT_A);
  k_swz_gate<<<dim3(256*NKT_D), dim3(64), 0, stream>>>(dWih, dWhh, WD, 1600, NKT_D);
  k_swz_qt <<<dim3(128), dim3(128), 0, stream>>>(qW, QWP);
  k_swz_loc<<<dim3(8),   dim3(64), 0, stream>>>(locW, WLOC);
  k_swz_proj<<<dim3(81), dim3(256), 0, stream>>>(projW, gateW, PJW);

  Par p;
  p.X2 = X2; p.PMEM = PMEM;
  p.WA = WA; p.WD = WD; p.WLOC = WLOC; p.MEMBT = MEMBT; p.PJW = PJW;
  p.X2F = X2F; p.QWP = QWP;
  p.BSA = BSA; p.BSD = BSD;
  p.convW = convW; p.convb = convb; p.vW = vW;
  p.projb = projb; p.gateb = gateb;
  p.mlen = mlen;
  p.AC = AC; p.DH = DH; p.CTX = CTX;
  p.AW = AW; p.AWC = AWC; p.EN = EN;
  p.out_mel = out_mel; p.out_gate = out_gate; p.out_align = out_align;
  p.FLAGS = FLAGS;

  (void)hipFuncSetAttribute((const void*)k_loop,
                            hipFuncAttributeMaxDynamicSharedMemorySize, LDS_TOTAL);
  k_loop<<<dim3(256), dim3(512), LDS_TOTAL, stream>>>(p);
}

// Round 9
// 32415.790 us; speedup vs baseline: 1.2923x; 1.2923x over previous
//
#include <hip/hip_runtime.h>
#include <stdint.h>

// ---------------------------------------------------------------------------
// Tacotron2-style decoder, 400 sequential steps. R12 = R9 + padded barrier
// flags (one per 128B cacheline).
//   R11 post-mortem: deleting A-pack made all 256 blocks live-gather AC/DH
//   f32 -> FETCH +47%, 41.4ms regression. R9's pack-once/broadcast-bf16 is
//   load-bearing; reverted to R9 (31.4ms champion).
//   R12 change: FLAGS stride 32 u32 (128B) per flag. R9 packed 16 flags per
//   64B line -> each gbar publish = 256 agent-scope stores into 16 lines,
//   LLC line-contention serialization. Private lines remove it.
// Phases/step: A: att-gates+cell(t), dec-gates+cell(t-1), conv;  B: q + proj;
//   C: energies (local recompute) + A-pack;  [sib-bar]  D: softmax + ctx.
// ---------------------------------------------------------------------------

#define NB  32
#define TI  512
#define ED  576
#define TO  400
#define NM  80
#define PR  256
#define AR  1024
#define DR  1024
#define AD  128
#define NFl 32
#define KSz 31
#define KA  1856      // 832 (x,ctx) + 1024 (h=c)
#define KD  2624      // 1600 (c,ctx) + 1024 (dh)
#define NKT_A 58      // KA/32
#define NKT_D 82      // KD/32
#define FPAD 32       // flag stride in u32 (128B/flag)
#define MF_OFF (257*FPAD)   // sibling-flag region base (after 256 + release)

// dynamic LDS layout (floats within scr)
//   [0..3583]   phase-shared: reduce8 slots / sG(512) / sIN(2048) / sAWI / eP
//   [3584..4607] sCwB conv out, [64][32] bf16  (persists A -> C)
//   [4608..4735] sACc att cell state (persistent)
//   [4736..4863] sDCc dec cell state (persistent)
//   [4864..4991] sQ
#define SCR_CWB 3584
#define SCR_ACC 4608
#define SCR_DCC 4736
#define SCR_SQ  4864
#define LDS_WA_BYTES (NKT_A*512*2)                    // 59392
#define LDS_WD_BYTES (NKT_D*512*2)                    // 83968
#define LDS_SCR_FLOATS 4992
#define LDS_TOTAL (LDS_WA_BYTES + LDS_WD_BYTES + LDS_SCR_FLOATS*4)  // 163328

typedef __attribute__((ext_vector_type(8))) short bf8_t;
typedef __attribute__((ext_vector_type(4))) float f4_t;
typedef __attribute__((ext_vector_type(2))) float f2_t;
typedef unsigned long long ull;

__device__ __forceinline__ short f2bf(float f){
  union { float f; unsigned u; } v; v.f = f;
  unsigned r = v.u + 0x7fffu + ((v.u >> 16) & 1u);
  return (short)(r >> 16);
}
__device__ __forceinline__ float bf2f(short s){
  union { unsigned u; float f; } v; v.u = ((unsigned)(unsigned short)s) << 16; return v.f;
}
__device__ __forceinline__ float sigm(float x){ return 1.f / (1.f + __expf(-x)); }

__device__ __forceinline__ f4_t MFMA(bf8_t a, bf8_t b, f4_t c){
  return __builtin_amdgcn_mfma_f32_16x16x32_bf16(a, b, c, 0, 0, 0);
}

// ---- coherent (agent-scope relaxed) accessors
__device__ __forceinline__ float cld(const float* p){
  return __hip_atomic_load(p, __ATOMIC_RELAXED, __HIP_MEMORY_SCOPE_AGENT);
}
__device__ __forceinline__ void cst(float* p, float v){
  __hip_atomic_store(p, v, __ATOMIC_RELAXED, __HIP_MEMORY_SCOPE_AGENT);
}
__device__ __forceinline__ ull cld8(const void* p){
  return __hip_atomic_load((const ull*)p, __ATOMIC_RELAXED, __HIP_MEMORY_SCOPE_AGENT);
}
__device__ __forceinline__ void cst8(void* p, ull v){
  __hip_atomic_store((ull*)p, v, __ATOMIC_RELAXED, __HIP_MEMORY_SCOPE_AGENT);
}
__device__ __forceinline__ bf8_t cld_bf8(const short* p){
  union { bf8_t v; ull q[2]; } u;
  u.q[0] = cld8(p); u.q[1] = cld8(p + 4);
  return u.v;
}
__device__ __forceinline__ void cst_bf8(short* p, bf8_t v){
  union { bf8_t v; ull q[2]; } u; u.v = v;
  cst8(p, u.q[0]); cst8(p + 4, u.q[1]);
}

__device__ __forceinline__ bf8_t packrow(const float* p){   // cached source
  f4_t a = *(const f4_t*)p;
  f4_t b = *(const f4_t*)(p + 4);
  bf8_t r;
  r[0]=f2bf(a[0]); r[1]=f2bf(a[1]); r[2]=f2bf(a[2]); r[3]=f2bf(a[3]);
  r[4]=f2bf(b[0]); r[5]=f2bf(b[1]); r[6]=f2bf(b[2]); r[7]=f2bf(b[3]);
  return r;
}
__device__ __forceinline__ bf8_t packrow_coh(const float* p){ // coherent source
  union { ull q; float f[2]; } u0, u1, u2, u3;
  u0.q = cld8(p); u1.q = cld8(p + 2); u2.q = cld8(p + 4); u3.q = cld8(p + 6);
  bf8_t r;
  r[0]=f2bf(u0.f[0]); r[1]=f2bf(u0.f[1]);
  r[2]=f2bf(u1.f[0]); r[3]=f2bf(u1.f[1]);
  r[4]=f2bf(u2.f[0]); r[5]=f2bf(u2.f[1]);
  r[6]=f2bf(u3.f[0]); r[7]=f2bf(u3.f[1]);
  return r;
}

struct Par {
  const float *X2, *PMEM;
  const short *WA, *WD, *WQ, *WLOC, *MEMBT, *PJW;
  const float *BSA, *BSD;
  const float *convW, *convb, *vW;
  const float *projb, *gateb;
  const int *mlen;
  float *AC, *DH, *CTX, *AW, *AWC, *EN, *QP;
  short *ABA, *ABD;
  float *out_mel, *out_gate, *out_align;
  unsigned *FLAGS;
};

// att input = [x_t(256) | ctx_{t-1}(576) | ac_{t-1}(1024)]; AC single-buffer
__device__ __forceinline__ const float* aptr_att(const Par& p, int rp, int t, int b, int k){
  if (k < PR)      return p.X2 + ((size_t)t*NB + b)*PR + k;
  if (k < PR+ED)   return p.CTX + (size_t)rp*NB*ED + b*ED + (k - PR);
  return p.AC + (size_t)b*AR + (k - PR - ED);
}

// dec A fragment for K-tile ks; ctx span live from CTX[cpar], ac/dh prepacked
__device__ __forceinline__ void loadD(const Par& p, int cpar, int ks, int lane,
                                      bf8_t& a0, bf8_t& a1){
  if (ks >= 32 && ks < 50){                            // ctx span (coherent)
    const int kb = ks*32 + ((lane >> 4) << 3);
    const float* c0 = p.CTX + (size_t)cpar*NB*ED + (size_t)(lane & 15)*ED + (kb - AR);
    const float* c1 = p.CTX + (size_t)cpar*NB*ED + (size_t)(16 + (lane & 15))*ED + (kb - AR);
    a0 = packrow_coh(c0);
    a1 = packrow_coh(c1);
  } else {                                             // pre-packed ac/dh
    a0 = cld_bf8(p.ABD + ((size_t)(0*NKT_D + ks)*64 + lane)*8);
    a1 = cld_bf8(p.ABD + ((size_t)(1*NKT_D + ks)*64 + lane)*8);
  }
}

// ---- centralized grid barrier; one flag per 128B cacheline -----------------
__device__ __forceinline__ void gbar(unsigned* flags, unsigned tgt){
  __syncthreads();
  if (threadIdx.x == 0)
    __hip_atomic_store(&flags[blockIdx.x*FPAD], tgt, __ATOMIC_RELAXED, __HIP_MEMORY_SCOPE_AGENT);
  if (blockIdx.x == 0){
    if (threadIdx.x < 256){
      while (__hip_atomic_load(&flags[threadIdx.x*FPAD], __ATOMIC_RELAXED, __HIP_MEMORY_SCOPE_AGENT) < tgt) {}
    }
    __syncthreads();
    if (threadIdx.x == 0)
      __hip_atomic_store(&flags[256*FPAD], tgt, __ATOMIC_RELAXED, __HIP_MEMORY_SCOPE_AGENT);
  }
  if (threadIdx.x == 0){
    while (__hip_atomic_load(&flags[256*FPAD], __ATOMIC_RELAXED, __HIP_MEMORY_SCOPE_AGENT) < tgt) {}
  }
  __syncthreads();
}

// ---- 8-sibling barrier: blocks (b*8 .. b*8+7); padded flags ----------------
__device__ __forceinline__ void sibbar(unsigned* mf, int bid, int tid, unsigned tgt){
  __syncthreads();
  if (tid == 0)
    __hip_atomic_store(&mf[bid*FPAD], tgt, __ATOMIC_RELAXED, __HIP_MEMORY_SCOPE_AGENT);
  const int g = (bid >> 3) << 3;
  if (tid < 8){
    while (__hip_atomic_load(&mf[(g + tid)*FPAD], __ATOMIC_RELAXED, __HIP_MEMORY_SCOPE_AGENT) < tgt) {}
  }
  __syncthreads();
}

// ---- 8-wave accumulator reduce -> wave 0 (LDS slots, waves 1..7 only) ------
__device__ __forceinline__ void reduce8(float* scr, f4_t& a0, f4_t& a1, int lane, int wv){
  if (wv > 0){
    float* slot = scr + (size_t)((wv - 1)*64 + lane)*8;
    *(f4_t*)slot       = a0;
    *(f4_t*)(slot + 4) = a1;
  }
  __syncthreads();
  if (wv == 0){
    #pragma unroll
    for (int w = 0; w < 7; ++w){
      const float* s2 = scr + (size_t)(w*64 + lane)*8;
      a0 += *(const f4_t*)s2;
      a1 += *(const f4_t*)(s2 + 4);
    }
  }
  __syncthreads();
}

// ---- dec gates GEMM + dec cell (block-local; units 4bid..4bid+3) -----------
__device__ __forceinline__ void dec_gates_cell(const Par& p, const short* sWD, float* scr,
                                               float* sDCc, int cpar, int bid,
                                               int lane, int wv, int tid){
  f4_t acc0 = (f4_t){0.f,0.f,0.f,0.f}, acc1 = (f4_t){0.f,0.f,0.f,0.f};
  { // batch 0: idx 0..5 (ks <= 47 < NKT_D always)
    bf8_t A0[6], A1[6];
    #pragma unroll
    for (int i = 0; i < 6; ++i) loadD(p, cpar, wv + i*8, lane, A0[i], A1[i]);
    #pragma unroll
    for (int i = 0; i < 6; ++i){
      const bf8_t bw = *((const bf8_t*)sWD + (wv + i*8)*64 + lane);
      acc0 = MFMA(A0[i], bw, acc0);
      acc1 = MFMA(A1[i], bw, acc1);
    }
  }
  { // batch 1: idx 6..10
    bf8_t A0[5], A1[5];
    #pragma unroll
    for (int i = 0; i < 5; ++i){
      const int ks = wv + (i + 6)*8;
      if (ks < NKT_D) loadD(p, cpar, ks, lane, A0[i], A1[i]);
    }
    #pragma unroll
    for (int i = 0; i < 5; ++i){
      const int ks = wv + (i + 6)*8;
      if (ks < NKT_D){
        const bf8_t bw = *((const bf8_t*)sWD + ks*64 + lane);
        acc0 = MFMA(A0[i], bw, acc0);
        acc1 = MFMA(A1[i], bw, acc1);
      }
    }
  }
  reduce8(scr, acc0, acc1, lane, wv);
  float* sG = scr;                                  // 512 floats, slots now dead
  if (wv == 0){
    const int col = lane & 15, rb2 = (lane >> 4) << 2;
    const int jp = (col & 3)*1024 + bid*4 + (col >> 2);
    const float bs = p.BSD[jp];
    #pragma unroll
    for (int r = 0; r < 4; ++r){
      sG[(rb2 + r)*16 + col]      = acc0[r] + bs;
      sG[(16 + rb2 + r)*16 + col] = acc1[r] + bs;
    }
  }
  __syncthreads();
  if (tid < 128){
    const int b = tid >> 2, ul = tid & 3;
    const float gi = sG[b*16 + ul*4 + 0];
    const float gf = sG[b*16 + ul*4 + 1];
    const float gg = sG[b*16 + ul*4 + 2];
    const float go = sG[b*16 + ul*4 + 3];
    const float c  = sigm(gf) * sDCc[tid] + sigm(gi) * tanhf(gg);
    sDCc[tid] = c;
    cst(&p.DH[(size_t)b*DR + bid*4 + ul], sigm(go) * tanhf(c));
  }
  __syncthreads();
}

// ---- mel/gate projection for step tprev (cell already done in phase A) -----
// sIN = [DH(1024) | CTX(576) | 0(448)]; PJW rows padded to 2048 with zeros.
__device__ void dec_proj(const Par& p, int b, int tprev, int tid, float* sIN){
  const float* ctxg = p.CTX + (size_t)(tprev & 1)*NB*ED + b*ED;
  float h0  = cld(&p.DH[(size_t)b*DR + tid]);
  float h1  = cld(&p.DH[(size_t)b*DR + 512 + tid]);
  float cx0 = cld(ctxg + tid);
  float cx1 = (tid < ED - 512) ? cld(ctxg + 512 + tid) : 0.f;
  sIN[tid] = h0; sIN[512 + tid] = h1;
  sIN[1024 + tid] = cx0;
  if (tid < ED - 512) sIN[1536 + tid] = cx1;
  if (tid < 448) sIN[1600 + tid] = 0.f;
  __syncthreads();
  const int lane = tid & 63, wv = tid >> 6;
  for (int o = wv; o < 81; o += 8){
    const short* wr = p.PJW + (size_t)o*2048 + lane*8;
    float s = 0.f;
    #pragma unroll
    for (int j = 0; j < 4; ++j){
      const bf8_t w8 = *(const bf8_t*)(wr + j*512);
      const float* v = sIN + j*512 + lane*8;
      s += v[0]*bf2f(w8[0]) + v[1]*bf2f(w8[1]) + v[2]*bf2f(w8[2]) + v[3]*bf2f(w8[3])
         + v[4]*bf2f(w8[4]) + v[5]*bf2f(w8[5]) + v[6]*bf2f(w8[6]) + v[7]*bf2f(w8[7]);
    }
    #pragma unroll
    for (int d = 32; d > 0; d >>= 1) s += __shfl_down(s, d);
    if (lane == 0){
      if (o < 80) p.out_mel[((size_t)b*NM + o)*TO + tprev] = s + p.projb[o];
      else        p.out_gate[(size_t)b*TO + tprev] = s + p.gateb[0];
    }
  }
  __syncthreads();
}

// ============================ persistent kernel =============================
__global__ __launch_bounds__(512) void k_loop(Par p){
  const int bid = blockIdx.x, tid = threadIdx.x;
  const int lane = tid & 63, wv = tid >> 6;

  extern __shared__ char dsm[];
  short* sWA = (short*)dsm;
  short* sWD = (short*)(dsm + LDS_WA_BYTES);
  float* scr = (float*)(dsm + LDS_WA_BYTES + LDS_WD_BYTES);
  float* sACc = scr + SCR_ACC;
  float* sDCc = scr + SCR_DCC;
  unsigned* mf = p.FLAGS + MF_OFF;

  // ---- one-time: weights -> LDS; cell-state init ---------------------------
  {
    if (tid < 128){ sACc[tid] = 0.f; sDCc[tid] = 0.f; }
    const bf8_t* gwa = (const bf8_t*)(p.WA + (size_t)bid*NKT_A*512);
    bf8_t* lwa = (bf8_t*)sWA;
    for (int i = tid; i < NKT_A*64; i += 512) lwa[i] = gwa[i];
    const bf8_t* gwd = (const bf8_t*)(p.WD + (size_t)bid*NKT_D*512);
    bf8_t* lwd = (bf8_t*)sWD;
    for (int i = tid; i < NKT_D*64; i += 512) lwd[i] = gwd[i];
    __syncthreads();
  }

  for (int t = 0; t < TO; ++t){
    const int wp = t & 1, rp = wp ^ 1;
    const unsigned base = (unsigned)(t * 3);

    // ------- PHASE A: att-gates+cell(t); dec-gates+cell(t-1); conv ---------
    {
      // --- att gates GEMM ---
      f4_t acc0 = (f4_t){0.f,0.f,0.f,0.f}, acc1 = (f4_t){0.f,0.f,0.f,0.f};
      bf8_t A0[8], A1[8];
      #pragma unroll
      for (int i = 0; i < 8; ++i){                     // batch-prefetch A
        const int ks = wv + i*8;
        if (ks < NKT_A){
          if (t == 0 || (ks >= 8 && ks < 26)){         // live gather
            const int kb = ks*32 + ((lane >> 4) << 3);
            const float* p0 = aptr_att(p, rp, t, lane & 15, kb);
            const float* p1 = aptr_att(p, rp, t, 16 + (lane & 15), kb);
            if (kb < PR){ A0[i] = packrow(p0);     A1[i] = packrow(p1);     }
            else        { A0[i] = packrow_coh(p0); A1[i] = packrow_coh(p1); }
          } else {                                     // pre-packed x/ac
            A0[i] = cld_bf8(p.ABA + ((size_t)(0*NKT_A + ks)*64 + lane)*8);
            A1[i] = cld_bf8(p.ABA + ((size_t)(1*NKT_A + ks)*64 + lane)*8);
          }
        }
      }
      #pragma unroll
      for (int i = 0; i < 8; ++i){
        const int ks = wv + i*8;
        if (ks < NKT_A){
          const bf8_t bw = *((const bf8_t*)sWA + ks*64 + lane);
          acc0 = MFMA(A0[i], bw, acc0);
          acc1 = MFMA(A1[i], bw, acc1);
        }
      }
      reduce8(scr, acc0, acc1, lane, wv);
      float* sG = scr;
      if (wv == 0){
        const int col = lane & 15, rb2 = (lane >> 4) << 2;
        const int jp = (col & 3)*1024 + bid*4 + (col >> 2);
        const float bs = p.BSA[jp];
        #pragma unroll
        for (int r = 0; r < 4; ++r){
          sG[(rb2 + r)*16 + col]      = acc0[r] + bs;
          sG[(16 + rb2 + r)*16 + col] = acc1[r] + bs;
        }
      }
      __syncthreads();
      if (tid < 128){                                  // att cell (h := c)
        const int b = tid >> 2, ul = tid & 3;
        const float gi = sG[b*16 + ul*4 + 0];
        const float gf = sG[b*16 + ul*4 + 1];
        const float gg = sG[b*16 + ul*4 + 2];
        const float c  = sigm(gf) * sACc[tid] + sigm(gi) * tanhf(gg);
        sACc[tid] = c;
        cst(&p.AC[(size_t)b*AR + bid*4 + ul], c);
      }
      __syncthreads();
      // --- dec gates + cell for t-1 ---
      if (t > 0) dec_gates_cell(p, sWD, scr, sDCc, rp, bid, lane, wv, tid);
      // --- location conv -> sCwB (persists to C) ---
      const int b = bid >> 3, tc = bid & 7, t0 = tc*64;
      float* sAWI = scr;                               // 188 floats (area dead)
      short* sCwB = (short*)(scr + SCR_CWB);           // [64][32] bf16
      for (int i = tid; i < 94; i += 512){
        int g = t0 - 15 + i;
        float a = 0.f, w = 0.f;
        if (g >= 0 && g < TI){
          a = cld(&p.AW [(size_t)rp*NB*TI + b*TI + g]);
          w = cld(&p.AWC[(size_t)rp*NB*TI + b*TI + g]);
        }
        sAWI[2*i] = a; sAWI[2*i + 1] = w;
      }
      __syncthreads();
      {
        const int wvu = __builtin_amdgcn_readfirstlane(wv);
        const int f0 = wvu * 4;
        float ac4[4];
        #pragma unroll
        for (int ff = 0; ff < 4; ++ff) ac4[ff] = p.convb[f0 + ff];
        for (int k = 0; k < KSz; ++k){
          f2_t a2 = *(const f2_t*)&sAWI[2*(lane + k)];
          #pragma unroll
          for (int ff = 0; ff < 4; ++ff){
            ac4[ff] += a2[0] * p.convW[((f0+ff)*2 + 0)*KSz + k]
                     + a2[1] * p.convW[((f0+ff)*2 + 1)*KSz + k];
          }
        }
        #pragma unroll
        for (int ff = 0; ff < 4; ++ff) sCwB[lane*32 + f0 + ff] = f2bf(ac4[ff]);
      }
    }
    gbar(p.FLAGS, base + 1);

    // ------- PHASE B: q (blk 0-31) + mel-proj(t-1) (blk 224-255) ------------
    {
      if (bid < 32){
        const int nt = bid >> 2, kc = bid & 3;
        const int kt = kc*8 + wv;
        const int kb = kt*32 + ((lane >> 4) << 3);
        bf8_t a0 = packrow_coh(p.AC + (size_t)(lane & 15)*AR + kb);
        bf8_t a1 = packrow_coh(p.AC + (size_t)(16 + (lane & 15))*AR + kb);
        const bf8_t bw = *(const bf8_t*)(p.WQ + ((size_t)(nt*32 + kt)*64 + lane)*8);
        f4_t q0 = (f4_t){0.f,0.f,0.f,0.f}, q1 = (f4_t){0.f,0.f,0.f,0.f};
        q0 = MFMA(a0, bw, q0);
        q1 = MFMA(a1, bw, q1);
        reduce8(scr, q0, q1, lane, wv);
        if (wv == 0){
          const int col = lane & 15, rb2 = (lane >> 4) << 2;
          float* qp = p.QP + (size_t)kc*NB*AD;
          #pragma unroll
          for (int r = 0; r < 4; ++r){
            cst(&qp[(rb2 + r)*AD + nt*16 + col],      q0[r]);
            cst(&qp[(16 + rb2 + r)*AD + nt*16 + col], q1[r]);
          }
        }
      }
      if (bid >= 224 && t > 0) dec_proj(p, bid - 224, t - 1, tid, scr);
    }
    gbar(p.FLAGS, base + 2);

    // ------- PHASE C: energies (local loc-proj recompute) + A-pack ----------
    {
      float* sQ = scr + SCR_SQ;
      if (tid < 128){
        const int b = bid >> 3;
        sQ[tid] = cld(&p.QP[(size_t)b*AD + tid])
                + cld(&p.QP[(size_t)NB*AD + b*AD + tid])
                + cld(&p.QP[(size_t)2*NB*AD + b*AD + tid])
                + cld(&p.QP[(size_t)3*NB*AD + b*AD + tid]);
      }
      // A-pack jobs: wave 0 of blocks 0..207 (one fragment-row each).
      if (wv == 0 && bid < 208){
        const int r = lane & 15, koff = (lane >> 4) << 3;
        if (bid < 80){
          if (t < TO - 1){  // att A for step t+1: x / ac parts
            const int m = bid / 40, idx = bid % 40;
            const int ks = (idx < 8) ? idx : idx + 18;       // skip ctx 8..25
            const int row = m*16 + r;
            const int k = ks*32 + koff;
            bf8_t v = (k < PR)
              ? packrow(p.X2 + ((size_t)(t+1)*NB + row)*PR + k)
              : packrow_coh(p.AC + (size_t)row*AR + (k - PR - ED));
            cst_bf8(p.ABA + ((size_t)(m*NKT_A + ks)*64 + lane)*8, v);
          }
        } else {            // dec A for this step: ac / dh parts
          const int j2 = bid - 80;
          const int m = j2 / 64, idx = j2 % 64;
          const int ks = (idx < 32) ? idx : idx + 18;        // skip ctx 32..49
          const int row = m*16 + r;
          const int k = ks*32 + koff;
          bf8_t v = (k < AR)
            ? packrow_coh(p.AC + (size_t)row*AR + k)
            : packrow_coh(p.DH + (size_t)row*DR + (k - AR - ED));
          cst_bf8(p.ABD + ((size_t)(m*NKT_D + ks)*64 + lane)*8, v);
        }
      }
      __syncthreads();
      // energies: per-wave 16-d slice; loc-proj MFMA recomputed from sCwB
      const int b = bid >> 3, tc = bid & 7, t0 = tc*64;
      short* sCwB = (short*)(scr + SCR_CWB);
      float* eP = scr;                                 // [8][64]
      const int g = lane >> 4, li = lane & 15;
      const int d2 = wv*16 + li;
      const float vw = p.vW[d2];
      const float qd = sQ[d2];
      const bf8_t bfr = *(const bf8_t*)(p.WLOC + (size_t)(wv*64 + lane)*8);
      #pragma unroll
      for (int mt = 0; mt < 4; ++mt){
        const bf8_t afr = *(const bf8_t*)(sCwB + (mt*16 + li)*32 + (g << 3));
        f4_t c = (f4_t){0.f,0.f,0.f,0.f};
        c = MFMA(afr, bfr, c);
        #pragma unroll
        for (int r = 0; r < 4; ++r){
          const int tg = t0 + mt*16 + g*4 + r;
          const float val = c[r] + p.PMEM[((size_t)b*TI + tg)*AD + d2];
          float v = vw * tanhf(qd + val);
          v += __shfl_xor(v, 1);
          v += __shfl_xor(v, 2);
          v += __shfl_xor(v, 4);
          v += __shfl_xor(v, 8);
          if (li == 0) eP[wv*64 + mt*16 + g*4 + r] = v;
        }
      }
      __syncthreads();
      if (tid < 64){
        float e = eP[tid];
        #pragma unroll
        for (int w2 = 1; w2 < 8; ++w2) e += eP[w2*64 + tid];
        const int tg = t0 + tid;
        cst(&p.EN[b*TI + tg], (tg < p.mlen[b]) ? e : -1e30f);
      }
    }
    sibbar(mf, bid, tid, (unsigned)(t + 1));    // only EN crosses C|D

    // ------- PHASE D: softmax (shfl) + context ------------------------------
    {
      const int b = bid >> 3, ec = bid & 7;
      float* red = scr;                          // 8 floats
      float* sp  = scr + 64;                     // 512 floats
      const float e = cld(&p.EN[b*TI + tid]);
      float m = e;
      #pragma unroll
      for (int d = 32; d > 0; d >>= 1) m = fmaxf(m, __shfl_xor(m, d));
      if (lane == 0) red[wv] = m;
      __syncthreads();
      const float M = fmaxf(fmaxf(fmaxf(red[0], red[1]), fmaxf(red[2], red[3])),
                            fmaxf(fmaxf(red[4], red[5]), fmaxf(red[6], red[7])));
      const float x = __expf(e - M);
      float z = x;
      #pragma unroll
      for (int d = 32; d > 0; d >>= 1) z += __shfl_xor(z, d);
      __syncthreads();
      if (lane == 0) red[wv] = z;
      __syncthreads();
      const float Z = red[0]+red[1]+red[2]+red[3]+red[4]+red[5]+red[6]+red[7];
      const float pv = x / Z;
      sp[tid] = pv;
      __syncthreads();
      if (ec == 0){
        cst(&p.AW [(size_t)wp*NB*TI + b*TI + tid], pv);
        cst(&p.AWC[(size_t)wp*NB*TI + b*TI + tid],
            cld(&p.AWC[(size_t)rp*NB*TI + b*TI + tid]) + pv);
        p.out_align[((size_t)b*TO + t)*TI + tid] = pv;
      }
      // ctx: transposed bf16 memory; one bf8 load/lane/row (reordered dot)
      #pragma unroll
      for (int ii = 0; ii < 9; ++ii){
        const int e2 = ec*72 + wv*9 + ii;
        const short* row = p.MEMBT + ((size_t)b*ED + e2)*TI;
        const bf8_t w8 = *(const bf8_t*)(row + lane*8);
        const float* v = sp + lane*8;
        float a2 = v[0]*bf2f(w8[0]) + v[1]*bf2f(w8[1]) + v[2]*bf2f(w8[2]) + v[3]*bf2f(w8[3])
                 + v[4]*bf2f(w8[4]) + v[5]*bf2f(w8[5]) + v[6]*bf2f(w8[6]) + v[7]*bf2f(w8[7]);
        #pragma unroll
        for (int d = 32; d > 0; d >>= 1) a2 += __shfl_down(a2, d);
        if (lane == 0)
          cst(&p.CTX[(size_t)wp*NB*ED + b*ED + e2], a2);
      }
    }
    gbar(p.FLAGS, base + 3);
  }

  // ---- tail: dec-gates+cell(TO-1), then mel-proj(TO-1) ---------------------
  dec_gates_cell(p, sWD, scr, sDCc, (TO - 1) & 1, bid, lane, wv, tid);
  gbar(p.FLAGS, (unsigned)(TO*3 + 1));
  if (bid >= 224) dec_proj(p, bid - 224, TO - 1, tid, scr);
}

// ============================ setup kernels =================================
__global__ __launch_bounds__(256) void k_init(float* z, int nz,
                                              float* bsa, const float* a1, const float* a2,
                                              float* bsd, const float* d1, const float* d2){
  const int idx = blockIdx.x*256 + threadIdx.x, st = gridDim.x*256;
  const int NG = 4096;
  for (int i = idx; i < nz; i += st) z[i] = 0.f;
  for (int i = idx; i < NG; i += st){ bsa[i] = a1[i] + a2[i]; bsd[i] = d1[i] + d2[i]; }
}

__global__ __launch_bounds__(256) void k_prenet1(const float* di, const float* W1, float* X1){
  const int t = blockIdx.x, tid = threadIdx.x;
  __shared__ float sdi[NB*NM];
  for (int i = tid; i < NB*NM; i += 256){
    const int b = i / NM, k = i - b*NM;
    sdi[i] = (t == 0) ? 0.f : di[((size_t)b*TO + (t-1))*NM + k];
  }
  __syncthreads();
  float acc[NB];
  #pragma unroll
  for (int b = 0; b < NB; ++b) acc[b] = 0.f;
  const int j = tid;
  for (int k = 0; k < NM; ++k){
    const float w = W1[j*NM + k];
    #pragma unroll
    for (int b = 0; b < NB; ++b) acc[b] += sdi[b*NM + k] * w;
  }
  for (int b = 0; b < NB; ++b)
    X1[((size_t)t*NB + b)*PR + j] = fmaxf(acc[b], 0.f);
}

__global__ __launch_bounds__(256) void k_prenet2(const float* X1, const float* W2, float* X2){
  const int t = blockIdx.x, tid = threadIdx.x;
  __shared__ float sx[NB*PR];
  for (int i = tid; i < NB*PR; i += 256) sx[i] = X1[(size_t)t*NB*PR + i];
  __syncthreads();
  float acc[NB];
  #pragma unroll
  for (int b = 0; b < NB; ++b) acc[b] = 0.f;
  const int j = tid;
  for (int k = 0; k < PR; ++k){
    const float w = W2[j*PR + k];
    #pragma unroll
    for (int b = 0; b < NB; ++b) acc[b] += sx[b*PR + k] * w;
  }
  for (int b = 0; b < NB; ++b)
    X2[((size_t)t*NB + b)*PR + j] = fmaxf(acc[b], 0.f);
}

__global__ __launch_bounds__(256) void k_pmem(const float* mem, const float* memW, float* pm){
  const int b = blockIdx.x >> 3, tc = blockIdx.x & 7, tid = threadIdx.x;
  __shared__ float sW[64*AD];
  __shared__ float sM[64*65];
  const int tl = tid >> 2, dq = tid & 3;
  float acc[32];
  #pragma unroll
  for (int i = 0; i < 32; ++i) acc[i] = 0.f;
  for (int kc = 0; kc < 9; ++kc){
    __syncthreads();
    for (int i = tid; i < 64*AD; i += 256){
      const int d = i >> 6, kl = i & 63;
      sW[kl*AD + ((d + kl) & 127)] = memW[(size_t)d*ED + kc*64 + kl];
    }
    for (int i = tid; i < 64*64; i += 256){
      const int tt = i >> 6, kl = i & 63;
      sM[tt*65 + kl] = mem[((size_t)b*TI + tc*64 + tt)*ED + kc*64 + kl];
    }
    __syncthreads();
    for (int kl = 0; kl < 64; ++kl){
      const float mv = sM[tl*65 + kl];
      #pragma unroll
      for (int d2 = 0; d2 < 32; ++d2)
        acc[d2] += mv * sW[kl*AD + ((dq*32 + d2 + kl) & 127)];
    }
  }
  for (int d2 = 0; d2 < 32; ++d2)
    pm[((size_t)b*TI + tc*64 + tl)*AD + dq*32 + d2] = acc[d2];
}

// memory -> bf16 transposed [b][e][t] (coalesced ctx matvec)
__global__ __launch_bounds__(256) void k_membt(const float* mem, short* mt){
  const int b = blockIdx.x / 36, ec = blockIdx.x % 36;
  __shared__ float sT[64*17];
  for (int tc = 0; tc < 8; ++tc){
    __syncthreads();
    for (int i = threadIdx.x; i < 64*16; i += 256){
      const int tt = i >> 4, e = i & 15;
      sT[tt*17 + e] = mem[((size_t)b*TI + tc*64 + tt)*ED + ec*16 + e];
    }
    __syncthreads();
    for (int i = threadIdx.x; i < 16*64; i += 256){
      const int e = i >> 6, tt = i & 63;
      mt[((size_t)b*ED + ec*16 + e)*TI + tc*64 + tt] = f2bf(sT[tt*17 + e]);
    }
  }
}

// weights -> bf16 MFMA B-fragment layout, gate-interleaved columns:
// tile nt, col nl: unit u = nt*4 + (nl>>2), gate gi = nl&3, row = gi*1024 + u
__global__ __launch_bounds__(64) void k_swz_gate(const float* Wih, const float* Whh,
                                                 short* dst, int split, int nkt){
  const int bidx = blockIdx.x;
  const int nt = bidx / nkt, kt = bidx - nt*nkt;
  const int lane = threadIdx.x;
  const int nl = lane & 15;
  const int jp = (nl & 3)*1024 + nt*4 + (nl >> 2);
  const int k0 = kt*32 + ((lane >> 4) << 3);
  bf8_t v;
  #pragma unroll
  for (int jj = 0; jj < 8; ++jj){
    const int k = k0 + jj;
    const float f = (k < split) ? Wih[(size_t)jp*split + k]
                                : Whh[(size_t)jp*1024 + (k - split)];
    v[jj] = f2bf(f);
  }
  *(bf8_t*)(dst + (size_t)bidx*512 + lane*8) = v;
}

__global__ __launch_bounds__(64) void k_swz_q(const float* qW, short* dst){
  const int bidx = blockIdx.x;                 // nt*32 + kt
  const int nt = bidx >> 5, kt = bidx & 31;
  const int lane = threadIdx.x;
  const int d = nt*16 + (lane & 15);
  const int k0 = kt*32 + ((lane >> 4) << 3);
  bf8_t v;
  #pragma unroll
  for (int jj = 0; jj < 8; ++jj) v[jj] = f2bf(qW[(size_t)d*AR + k0 + jj]);
  *(bf8_t*)(dst + (size_t)bidx*512 + lane*8) = v;
}

__global__ __launch_bounds__(64) void k_swz_loc(const float* locW, short* dst){
  const int nt = blockIdx.x;                   // 0..7
  const int lane = threadIdx.x;
  const int d = nt*16 + (lane & 15);
  const int f0 = (lane >> 4) << 3;
  bf8_t v;
  #pragma unroll
  for (int jj = 0; jj < 8; ++jj) v[jj] = f2bf(locW[d*NFl + f0 + jj]);
  *(bf8_t*)(dst + (size_t)(nt*64 + lane)*8) = v;
}

// projW(80x1600) + gateW(1x1600) -> bf16 rows, padded to stride 2048 (zeros)
__global__ __launch_bounds__(256) void k_swz_proj(const float* projW, const float* gateW,
                                                  short* dst){
  const int o = blockIdx.x;                    // 0..80
  const float* src = (o < 80) ? (projW + (size_t)o*1600) : gateW;
  for (int k = threadIdx.x; k < 2048; k += 256)
    dst[(size_t)o*2048 + k] = (k < 1600) ? f2bf(src[k]) : (short)0;
}

// ============================== launch ======================================
extern "C" void kernel_launch(void* const* d_in, const int* in_sizes, int n_in,
                              void* d_out, int out_size, void* d_ws, size_t ws_size,
                              hipStream_t stream){
  const float* mem    = (const float*)d_in[0];
  const float* dec_in = (const float*)d_in[1];
  const float* pW1    = (const float*)d_in[2];
  const float* pW2    = (const float*)d_in[3];
  const float* aWih   = (const float*)d_in[4];
  const float* aWhh   = (const float*)d_in[5];
  const float* aBih   = (const float*)d_in[6];
  const float* aBhh   = (const float*)d_in[7];
  const float* qW     = (const float*)d_in[8];
  const float* memW   = (const float*)d_in[9];
  const float* convW  = (const float*)d_in[10];
  const float* convb  = (const float*)d_in[11];
  const float* locW   = (const float*)d_in[12];
  const float* vW     = (const float*)d_in[13];
  const float* dWih   = (const float*)d_in[14];
  const float* dWhh   = (const float*)d_in[15];
  const float* dBih   = (const float*)d_in[16];
  const float* dBhh   = (const float*)d_in[17];
  const float* projW  = (const float*)d_in[18];
  const float* projb  = (const float*)d_in[19];
  const float* gateW  = (const float*)d_in[20];
  const float* gateb  = (const float*)d_in[21];
  const int*   mlen   = (const int*)d_in[22];
  (void)in_sizes; (void)n_in; (void)out_size; (void)ws_size;

  char* basep = (char*)d_ws;
  size_t off = 0;
  auto carve = [&](size_t bytes) -> char* {
    char* r = basep + off;
    off = (off + bytes + 255) & ~(size_t)255;
    return r;
  };
  const int NG = 4096;
  short* WA    = (short*)carve((size_t)NG*KA*2);
  short* WD    = (short*)carve((size_t)NG*KD*2);
  short* WQ    = (short*)carve((size_t)AD*AR*2);
  short* WLOC  = (short*)carve((size_t)AD*NFl*2);
  short* MEMBT = (short*)carve((size_t)NB*TI*ED*2);
  short* PJW   = (short*)carve((size_t)81*2048*2);
  float* X1    = (float*)carve((size_t)TO*NB*PR*4);
  float* X2    = (float*)carve((size_t)TO*NB*PR*4);
  float* PMEM  = (float*)carve((size_t)NB*TI*AD*4);
  float* BSA   = (float*)carve((size_t)NG*4);
  float* BSD   = (float*)carve((size_t)NG*4);
  short* ABA   = (short*)carve((size_t)2*NKT_A*512*2);
  short* ABD   = (short*)carve((size_t)2*NKT_D*512*2);
  // ---- zero-span begins here (contiguous through FLAGS) ----
  float* AC    = (float*)carve((size_t)NB*AR*4);
  float* DH    = (float*)carve((size_t)NB*DR*4);
  float* CTX   = (float*)carve((size_t)2*NB*ED*4);
  float* AW    = (float*)carve((size_t)2*NB*TI*4);
  float* AWC   = (float*)carve((size_t)2*NB*TI*4);
  float* EN    = (float*)carve((size_t)NB*TI*4);
  float* QP    = (float*)carve((size_t)4*NB*AD*4);
  unsigned* FLAGS = (unsigned*)carve((size_t)(MF_OFF + 256*FPAD)*4);
  const int nz = (int)((((char*)FLAGS + (size_t)(MF_OFF + 256*FPAD)*4) - (char*)AC) / 4);

  float* out_mel   = (float*)d_out;
  float* out_gate  = out_mel + (size_t)NB*NM*TO;
  float* out_align = out_gate + (size_t)NB*TO;

  k_init   <<<dim3(512), dim3(256), 0, stream>>>(AC, nz, BSA, aBih, aBhh, BSD, dBih, dBhh);
  k_prenet1<<<dim3(TO),  dim3(256), 0, stream>>>(dec_in, pW1, X1);
  k_prenet2<<<dim3(TO),  dim3(256), 0, stream>>>(X1, pW2, X2);
  k_pmem   <<<dim3(256), dim3(256), 0, stream>>>(mem, memW, PMEM);
  k_membt  <<<dim3(NB*36), dim3(256), 0, stream>>>(mem, MEMBT);
  k_swz_gate<<<dim3(256*NKT_A), dim3(64), 0, stream>>>(aWih, aWhh, WA, 832, NKT_A);
  k_swz_gate<<<dim3(256*NKT_D), dim3(64), 0, stream>>>(dWih, dWhh, WD, 1600, NKT_D);
  k_swz_q  <<<dim3(256), dim3(64), 0, stream>>>(qW, WQ);
  k_swz_loc<<<dim3(8),   dim3(64), 0, stream>>>(locW, WLOC);
  k_swz_proj<<<dim3(81), dim3(256), 0, stream>>>(projW, gateW, PJW);

  Par p;
  p.X2 = X2; p.PMEM = PMEM;
  p.WA = WA; p.WD = WD; p.WQ = WQ; p.WLOC = WLOC; p.MEMBT = MEMBT; p.PJW = PJW;
  p.BSA = BSA; p.BSD = BSD;
  p.convW = convW; p.convb = convb; p.vW = vW;
  p.projb = projb; p.gateb = gateb;
  p.mlen = mlen;
  p.AC = AC; p.DH = DH; p.CTX = CTX;
  p.AW = AW; p.AWC = AWC; p.EN = EN; p.QP = QP;
  p.ABA = ABA; p.ABD = ABD;
  p.out_mel = out_mel; p.out_gate = out_gate; p.out_align = out_align;
  p.FLAGS = FLAGS;

  (void)hipFuncSetAttribute((const void*)k_loop,
                            hipFuncAttributeMaxDynamicSharedMemorySize, LDS_TOTAL);
  k_loop<<<dim3(256), dim3(512), LDS_TOTAL, stream>>>(p);
}

// Round 10
// 30236.984 us; speedup vs baseline: 1.3854x; 1.0721x over previous
//
#include <hip/hip_runtime.h>
#include <stdint.h>

// ---------------------------------------------------------------------------
// Tacotron2-style decoder, 400 sequential steps. R13 = R12 + PMEM in bf16.
//   R12 post-mortem: padded flags null (31.4ms == R9). Re-derived from
//   counters: FETCH = 39MB/step of *L2* fills (TCC counts fills, not HBM);
//   per-XCD recurring read set = MEMBT 2.36 + PMEM 1.05 + ABA/ABD 0.29 +
//   PJW 0.33 + state ~0.3 = 4.3MB > 4MB L2 -> marginal thrash, every read
//   re-fills from L3 at ~700cy. That capacity overshoot explains every
//   previous null (conflicts/slack/phases/flags were all downstream).
//   R13: PMEM f32 -> bf16 (PMEMH): per-XCD set ~3.8MB < 4MB, tipping
//   MEMBT/PMEM/ABA/ABD into L2 residency across steps. PMEM loads in C
//   batched (16 in flight) ahead of the tanh/shfl chain.
// Phases/step: A: att-gates+cell(t), dec-gates+cell(t-1), conv;  B: q + proj;
//   C: energies (local recompute) + A-pack;  [sib-bar]  D: softmax + ctx.
// ---------------------------------------------------------------------------

#define NB  32
#define TI  512
#define ED  576
#define TO  400
#define NM  80
#define PR  256
#define AR  1024
#define DR  1024
#define AD  128
#define NFl 32
#define KSz 31
#define KA  1856      // 832 (x,ctx) + 1024 (h=c)
#define KD  2624      // 1600 (c,ctx) + 1024 (dh)
#define NKT_A 58      // KA/32
#define NKT_D 82      // KD/32
#define FPAD 32       // flag stride in u32 (128B/flag)
#define MF_OFF (257*FPAD)   // sibling-flag region base (after 256 + release)

// dynamic LDS layout (floats within scr)
//   [0..3583]   phase-shared: reduce8 slots / sG(512) / sIN(2048) / sAWI / eP
//   [3584..4607] sCwB conv out, [64][32] bf16  (persists A -> C)
//   [4608..4735] sACc att cell state (persistent)
//   [4736..4863] sDCc dec cell state (persistent)
//   [4864..4991] sQ
#define SCR_CWB 3584
#define SCR_ACC 4608
#define SCR_DCC 4736
#define SCR_SQ  4864
#define LDS_WA_BYTES (NKT_A*512*2)                    // 59392
#define LDS_WD_BYTES (NKT_D*512*2)                    // 83968
#define LDS_SCR_FLOATS 4992
#define LDS_TOTAL (LDS_WA_BYTES + LDS_WD_BYTES + LDS_SCR_FLOATS*4)  // 163328

typedef __attribute__((ext_vector_type(8))) short bf8_t;
typedef __attribute__((ext_vector_type(4))) float f4_t;
typedef __attribute__((ext_vector_type(2))) float f2_t;
typedef unsigned long long ull;

__device__ __forceinline__ short f2bf(float f){
  union { float f; unsigned u; } v; v.f = f;
  unsigned r = v.u + 0x7fffu + ((v.u >> 16) & 1u);
  return (short)(r >> 16);
}
__device__ __forceinline__ float bf2f(short s){
  union { unsigned u; float f; } v; v.u = ((unsigned)(unsigned short)s) << 16; return v.f;
}
__device__ __forceinline__ float sigm(float x){ return 1.f / (1.f + __expf(-x)); }

__device__ __forceinline__ f4_t MFMA(bf8_t a, bf8_t b, f4_t c){
  return __builtin_amdgcn_mfma_f32_16x16x32_bf16(a, b, c, 0, 0, 0);
}

// ---- coherent (agent-scope relaxed) accessors
__device__ __forceinline__ float cld(const float* p){
  return __hip_atomic_load(p, __ATOMIC_RELAXED, __HIP_MEMORY_SCOPE_AGENT);
}
__device__ __forceinline__ void cst(float* p, float v){
  __hip_atomic_store(p, v, __ATOMIC_RELAXED, __HIP_MEMORY_SCOPE_AGENT);
}
__device__ __forceinline__ ull cld8(const void* p){
  return __hip_atomic_load((const ull*)p, __ATOMIC_RELAXED, __HIP_MEMORY_SCOPE_AGENT);
}
__device__ __forceinline__ void cst8(void* p, ull v){
  __hip_atomic_store((ull*)p, v, __ATOMIC_RELAXED, __HIP_MEMORY_SCOPE_AGENT);
}
__device__ __forceinline__ bf8_t cld_bf8(const short* p){
  union { bf8_t v; ull q[2]; } u;
  u.q[0] = cld8(p); u.q[1] = cld8(p + 4);
  return u.v;
}
__device__ __forceinline__ void cst_bf8(short* p, bf8_t v){
  union { bf8_t v; ull q[2]; } u; u.v = v;
  cst8(p, u.q[0]); cst8(p + 4, u.q[1]);
}

__device__ __forceinline__ bf8_t packrow(const float* p){   // cached source
  f4_t a = *(const f4_t*)p;
  f4_t b = *(const f4_t*)(p + 4);
  bf8_t r;
  r[0]=f2bf(a[0]); r[1]=f2bf(a[1]); r[2]=f2bf(a[2]); r[3]=f2bf(a[3]);
  r[4]=f2bf(b[0]); r[5]=f2bf(b[1]); r[6]=f2bf(b[2]); r[7]=f2bf(b[3]);
  return r;
}
__device__ __forceinline__ bf8_t packrow_coh(const float* p){ // coherent source
  union { ull q; float f[2]; } u0, u1, u2, u3;
  u0.q = cld8(p); u1.q = cld8(p + 2); u2.q = cld8(p + 4); u3.q = cld8(p + 6);
  bf8_t r;
  r[0]=f2bf(u0.f[0]); r[1]=f2bf(u0.f[1]);
  r[2]=f2bf(u1.f[0]); r[3]=f2bf(u1.f[1]);
  r[4]=f2bf(u2.f[0]); r[5]=f2bf(u2.f[1]);
  r[6]=f2bf(u3.f[0]); r[7]=f2bf(u3.f[1]);
  return r;
}

struct Par {
  const float *X2;
  const short *PMEMH;
  const short *WA, *WD, *WQ, *WLOC, *MEMBT, *PJW;
  const float *BSA, *BSD;
  const float *convW, *convb, *vW;
  const float *projb, *gateb;
  const int *mlen;
  float *AC, *DH, *CTX, *AW, *AWC, *EN, *QP;
  short *ABA, *ABD;
  float *out_mel, *out_gate, *out_align;
  unsigned *FLAGS;
};

// att input = [x_t(256) | ctx_{t-1}(576) | ac_{t-1}(1024)]; AC single-buffer
__device__ __forceinline__ const float* aptr_att(const Par& p, int rp, int t, int b, int k){
  if (k < PR)      return p.X2 + ((size_t)t*NB + b)*PR + k;
  if (k < PR+ED)   return p.CTX + (size_t)rp*NB*ED + b*ED + (k - PR);
  return p.AC + (size_t)b*AR + (k - PR - ED);
}

// dec A fragment for K-tile ks; ctx span live from CTX[cpar], ac/dh prepacked
__device__ __forceinline__ void loadD(const Par& p, int cpar, int ks, int lane,
                                      bf8_t& a0, bf8_t& a1){
  if (ks >= 32 && ks < 50){                            // ctx span (coherent)
    const int kb = ks*32 + ((lane >> 4) << 3);
    const float* c0 = p.CTX + (size_t)cpar*NB*ED + (size_t)(lane & 15)*ED + (kb - AR);
    const float* c1 = p.CTX + (size_t)cpar*NB*ED + (size_t)(16 + (lane & 15))*ED + (kb - AR);
    a0 = packrow_coh(c0);
    a1 = packrow_coh(c1);
  } else {                                             // pre-packed ac/dh
    a0 = cld_bf8(p.ABD + ((size_t)(0*NKT_D + ks)*64 + lane)*8);
    a1 = cld_bf8(p.ABD + ((size_t)(1*NKT_D + ks)*64 + lane)*8);
  }
}

// ---- centralized grid barrier; one flag per 128B cacheline -----------------
__device__ __forceinline__ void gbar(unsigned* flags, unsigned tgt){
  __syncthreads();
  if (threadIdx.x == 0)
    __hip_atomic_store(&flags[blockIdx.x*FPAD], tgt, __ATOMIC_RELAXED, __HIP_MEMORY_SCOPE_AGENT);
  if (blockIdx.x == 0){
    if (threadIdx.x < 256){
      while (__hip_atomic_load(&flags[threadIdx.x*FPAD], __ATOMIC_RELAXED, __HIP_MEMORY_SCOPE_AGENT) < tgt) {}
    }
    __syncthreads();
    if (threadIdx.x == 0)
      __hip_atomic_store(&flags[256*FPAD], tgt, __ATOMIC_RELAXED, __HIP_MEMORY_SCOPE_AGENT);
  }
  if (threadIdx.x == 0){
    while (__hip_atomic_load(&flags[256*FPAD], __ATOMIC_RELAXED, __HIP_MEMORY_SCOPE_AGENT) < tgt) {}
  }
  __syncthreads();
}

// ---- 8-sibling barrier: blocks (b*8 .. b*8+7); padded flags ----------------
__device__ __forceinline__ void sibbar(unsigned* mf, int bid, int tid, unsigned tgt){
  __syncthreads();
  if (tid == 0)
    __hip_atomic_store(&mf[bid*FPAD], tgt, __ATOMIC_RELAXED, __HIP_MEMORY_SCOPE_AGENT);
  const int g = (bid >> 3) << 3;
  if (tid < 8){
    while (__hip_atomic_load(&mf[(g + tid)*FPAD], __ATOMIC_RELAXED, __HIP_MEMORY_SCOPE_AGENT) < tgt) {}
  }
  __syncthreads();
}

// ---- 8-wave accumulator reduce -> wave 0 (LDS slots, waves 1..7 only) ------
__device__ __forceinline__ void reduce8(float* scr, f4_t& a0, f4_t& a1, int lane, int wv){
  if (wv > 0){
    float* slot = scr + (size_t)((wv - 1)*64 + lane)*8;
    *(f4_t*)slot       = a0;
    *(f4_t*)(slot + 4) = a1;
  }
  __syncthreads();
  if (wv == 0){
    #pragma unroll
    for (int w = 0; w < 7; ++w){
      const float* s2 = scr + (size_t)(w*64 + lane)*8;
      a0 += *(const f4_t*)s2;
      a1 += *(const f4_t*)(s2 + 4);
    }
  }
  __syncthreads();
}

// ---- dec gates GEMM + dec cell (block-local; units 4bid..4bid+3) -----------
__device__ __forceinline__ void dec_gates_cell(const Par& p, const short* sWD, float* scr,
                                               float* sDCc, int cpar, int bid,
                                               int lane, int wv, int tid){
  f4_t acc0 = (f4_t){0.f,0.f,0.f,0.f}, acc1 = (f4_t){0.f,0.f,0.f,0.f};
  { // batch 0: idx 0..5 (ks <= 47 < NKT_D always)
    bf8_t A0[6], A1[6];
    #pragma unroll
    for (int i = 0; i < 6; ++i) loadD(p, cpar, wv + i*8, lane, A0[i], A1[i]);
    #pragma unroll
    for (int i = 0; i < 6; ++i){
      const bf8_t bw = *((const bf8_t*)sWD + (wv + i*8)*64 + lane);
      acc0 = MFMA(A0[i], bw, acc0);
      acc1 = MFMA(A1[i], bw, acc1);
    }
  }
  { // batch 1: idx 6..10
    bf8_t A0[5], A1[5];
    #pragma unroll
    for (int i = 0; i < 5; ++i){
      const int ks = wv + (i + 6)*8;
      if (ks < NKT_D) loadD(p, cpar, ks, lane, A0[i], A1[i]);
    }
    #pragma unroll
    for (int i = 0; i < 5; ++i){
      const int ks = wv + (i + 6)*8;
      if (ks < NKT_D){
        const bf8_t bw = *((const bf8_t*)sWD + ks*64 + lane);
        acc0 = MFMA(A0[i], bw, acc0);
        acc1 = MFMA(A1[i], bw, acc1);
      }
    }
  }
  reduce8(scr, acc0, acc1, lane, wv);
  float* sG = scr;                                  // 512 floats, slots now dead
  if (wv == 0){
    const int col = lane & 15, rb2 = (lane >> 4) << 2;
    const int jp = (col & 3)*1024 + bid*4 + (col >> 2);
    const float bs = p.BSD[jp];
    #pragma unroll
    for (int r = 0; r < 4; ++r){
      sG[(rb2 + r)*16 + col]      = acc0[r] + bs;
      sG[(16 + rb2 + r)*16 + col] = acc1[r] + bs;
    }
  }
  __syncthreads();
  if (tid < 128){
    const int b = tid >> 2, ul = tid & 3;
    const float gi = sG[b*16 + ul*4 + 0];
    const float gf = sG[b*16 + ul*4 + 1];
    const float gg = sG[b*16 + ul*4 + 2];
    const float go = sG[b*16 + ul*4 + 3];
    const float c  = sigm(gf) * sDCc[tid] + sigm(gi) * tanhf(gg);
    sDCc[tid] = c;
    cst(&p.DH[(size_t)b*DR + bid*4 + ul], sigm(go) * tanhf(c));
  }
  __syncthreads();
}

// ---- mel/gate projection for step tprev (cell already done in phase A) -----
// sIN = [DH(1024) | CTX(576) | 0(448)]; PJW rows padded to 2048 with zeros.
__device__ void dec_proj(const Par& p, int b, int tprev, int tid, float* sIN){
  const float* ctxg = p.CTX + (size_t)(tprev & 1)*NB*ED + b*ED;
  float h0  = cld(&p.DH[(size_t)b*DR + tid]);
  float h1  = cld(&p.DH[(size_t)b*DR + 512 + tid]);
  float cx0 = cld(ctxg + tid);
  float cx1 = (tid < ED - 512) ? cld(ctxg + 512 + tid) : 0.f;
  sIN[tid] = h0; sIN[512 + tid] = h1;
  sIN[1024 + tid] = cx0;
  if (tid < ED - 512) sIN[1536 + tid] = cx1;
  if (tid < 448) sIN[1600 + tid] = 0.f;
  __syncthreads();
  const int lane = tid & 63, wv = tid >> 6;
  for (int o = wv; o < 81; o += 8){
    const short* wr = p.PJW + (size_t)o*2048 + lane*8;
    float s = 0.f;
    #pragma unroll
    for (int j = 0; j < 4; ++j){
      const bf8_t w8 = *(const bf8_t*)(wr + j*512);
      const float* v = sIN + j*512 + lane*8;
      s += v[0]*bf2f(w8[0]) + v[1]*bf2f(w8[1]) + v[2]*bf2f(w8[2]) + v[3]*bf2f(w8[3])
         + v[4]*bf2f(w8[4]) + v[5]*bf2f(w8[5]) + v[6]*bf2f(w8[6]) + v[7]*bf2f(w8[7]);
    }
    #pragma unroll
    for (int d = 32; d > 0; d >>= 1) s += __shfl_down(s, d);
    if (lane == 0){
      if (o < 80) p.out_mel[((size_t)b*NM + o)*TO + tprev] = s + p.projb[o];
      else        p.out_gate[(size_t)b*TO + tprev] = s + p.gateb[0];
    }
  }
  __syncthreads();
}

// ============================ persistent kernel =============================
__global__ __launch_bounds__(512) void k_loop(Par p){
  const int bid = blockIdx.x, tid = threadIdx.x;
  const int lane = tid & 63, wv = tid >> 6;

  extern __shared__ char dsm[];
  short* sWA = (short*)dsm;
  short* sWD = (short*)(dsm + LDS_WA_BYTES);
  float* scr = (float*)(dsm + LDS_WA_BYTES + LDS_WD_BYTES);
  float* sACc = scr + SCR_ACC;
  float* sDCc = scr + SCR_DCC;
  unsigned* mf = p.FLAGS + MF_OFF;

  // ---- one-time: weights -> LDS; cell-state init ---------------------------
  {
    if (tid < 128){ sACc[tid] = 0.f; sDCc[tid] = 0.f; }
    const bf8_t* gwa = (const bf8_t*)(p.WA + (size_t)bid*NKT_A*512);
    bf8_t* lwa = (bf8_t*)sWA;
    for (int i = tid; i < NKT_A*64; i += 512) lwa[i] = gwa[i];
    const bf8_t* gwd = (const bf8_t*)(p.WD + (size_t)bid*NKT_D*512);
    bf8_t* lwd = (bf8_t*)sWD;
    for (int i = tid; i < NKT_D*64; i += 512) lwd[i] = gwd[i];
    __syncthreads();
  }

  for (int t = 0; t < TO; ++t){
    const int wp = t & 1, rp = wp ^ 1;
    const unsigned base = (unsigned)(t * 3);

    // ------- PHASE A: att-gates+cell(t); dec-gates+cell(t-1); conv ---------
    {
      // --- att gates GEMM ---
      f4_t acc0 = (f4_t){0.f,0.f,0.f,0.f}, acc1 = (f4_t){0.f,0.f,0.f,0.f};
      bf8_t A0[8], A1[8];
      #pragma unroll
      for (int i = 0; i < 8; ++i){                     // batch-prefetch A
        const int ks = wv + i*8;
        if (ks < NKT_A){
          if (t == 0 || (ks >= 8 && ks < 26)){         // live gather
            const int kb = ks*32 + ((lane >> 4) << 3);
            const float* p0 = aptr_att(p, rp, t, lane & 15, kb);
            const float* p1 = aptr_att(p, rp, t, 16 + (lane & 15), kb);
            if (kb < PR){ A0[i] = packrow(p0);     A1[i] = packrow(p1);     }
            else        { A0[i] = packrow_coh(p0); A1[i] = packrow_coh(p1); }
          } else {                                     // pre-packed x/ac
            A0[i] = cld_bf8(p.ABA + ((size_t)(0*NKT_A + ks)*64 + lane)*8);
            A1[i] = cld_bf8(p.ABA + ((size_t)(1*NKT_A + ks)*64 + lane)*8);
          }
        }
      }
      #pragma unroll
      for (int i = 0; i < 8; ++i){
        const int ks = wv + i*8;
        if (ks < NKT_A){
          const bf8_t bw = *((const bf8_t*)sWA + ks*64 + lane);
          acc0 = MFMA(A0[i], bw, acc0);
          acc1 = MFMA(A1[i], bw, acc1);
        }
      }
      reduce8(scr, acc0, acc1, lane, wv);
      float* sG = scr;
      if (wv == 0){
        const int col = lane & 15, rb2 = (lane >> 4) << 2;
        const int jp = (col & 3)*1024 + bid*4 + (col >> 2);
        const float bs = p.BSA[jp];
        #pragma unroll
        for (int r = 0; r < 4; ++r){
          sG[(rb2 + r)*16 + col]      = acc0[r] + bs;
          sG[(16 + rb2 + r)*16 + col] = acc1[r] + bs;
        }
      }
      __syncthreads();
      if (tid < 128){                                  // att cell (h := c)
        const int b = tid >> 2, ul = tid & 3;
        const float gi = sG[b*16 + ul*4 + 0];
        const float gf = sG[b*16 + ul*4 + 1];
        const float gg = sG[b*16 + ul*4 + 2];
        const float c  = sigm(gf) * sACc[tid] + sigm(gi) * tanhf(gg);
        sACc[tid] = c;
        cst(&p.AC[(size_t)b*AR + bid*4 + ul], c);
      }
      __syncthreads();
      // --- dec gates + cell for t-1 ---
      if (t > 0) dec_gates_cell(p, sWD, scr, sDCc, rp, bid, lane, wv, tid);
      // --- location conv -> sCwB (persists to C) ---
      const int b = bid >> 3, tc = bid & 7, t0 = tc*64;
      float* sAWI = scr;                               // 188 floats (area dead)
      short* sCwB = (short*)(scr + SCR_CWB);           // [64][32] bf16
      for (int i = tid; i < 94; i += 512){
        int g = t0 - 15 + i;
        float a = 0.f, w = 0.f;
        if (g >= 0 && g < TI){
          a = cld(&p.AW [(size_t)rp*NB*TI + b*TI + g]);
          w = cld(&p.AWC[(size_t)rp*NB*TI + b*TI + g]);
        }
        sAWI[2*i] = a; sAWI[2*i + 1] = w;
      }
      __syncthreads();
      {
        const int wvu = __builtin_amdgcn_readfirstlane(wv);
        const int f0 = wvu * 4;
        float ac4[4];
        #pragma unroll
        for (int ff = 0; ff < 4; ++ff) ac4[ff] = p.convb[f0 + ff];
        for (int k = 0; k < KSz; ++k){
          f2_t a2 = *(const f2_t*)&sAWI[2*(lane + k)];
          #pragma unroll
          for (int ff = 0; ff < 4; ++ff){
            ac4[ff] += a2[0] * p.convW[((f0+ff)*2 + 0)*KSz + k]
                     + a2[1] * p.convW[((f0+ff)*2 + 1)*KSz + k];
          }
        }
        #pragma unroll
        for (int ff = 0; ff < 4; ++ff) sCwB[lane*32 + f0 + ff] = f2bf(ac4[ff]);
      }
    }
    gbar(p.FLAGS, base + 1);

    // ------- PHASE B: q (blk 0-31) + mel-proj(t-1) (blk 224-255) ------------
    {
      if (bid < 32){
        const int nt = bid >> 2, kc = bid & 3;
        const int kt = kc*8 + wv;
        const int kb = kt*32 + ((lane >> 4) << 3);
        bf8_t a0 = packrow_coh(p.AC + (size_t)(lane & 15)*AR + kb);
        bf8_t a1 = packrow_coh(p.AC + (size_t)(16 + (lane & 15))*AR + kb);
        const bf8_t bw = *(const bf8_t*)(p.WQ + ((size_t)(nt*32 + kt)*64 + lane)*8);
        f4_t q0 = (f4_t){0.f,0.f,0.f,0.f}, q1 = (f4_t){0.f,0.f,0.f,0.f};
        q0 = MFMA(a0, bw, q0);
        q1 = MFMA(a1, bw, q1);
        reduce8(scr, q0, q1, lane, wv);
        if (wv == 0){
          const int col = lane & 15, rb2 = (lane >> 4) << 2;
          float* qp = p.QP + (size_t)kc*NB*AD;
          #pragma unroll
          for (int r = 0; r < 4; ++r){
            cst(&qp[(rb2 + r)*AD + nt*16 + col],      q0[r]);
            cst(&qp[(16 + rb2 + r)*AD + nt*16 + col], q1[r]);
          }
        }
      }
      if (bid >= 224 && t > 0) dec_proj(p, bid - 224, t - 1, tid, scr);
    }
    gbar(p.FLAGS, base + 2);

    // ------- PHASE C: energies (local loc-proj recompute) + A-pack ----------
    {
      float* sQ = scr + SCR_SQ;
      if (tid < 128){
        const int b = bid >> 3;
        sQ[tid] = cld(&p.QP[(size_t)b*AD + tid])
                + cld(&p.QP[(size_t)NB*AD + b*AD + tid])
                + cld(&p.QP[(size_t)2*NB*AD + b*AD + tid])
                + cld(&p.QP[(size_t)3*NB*AD + b*AD + tid]);
      }
      // A-pack jobs: wave 0 of blocks 0..207 (one fragment-row each).
      if (wv == 0 && bid < 208){
        const int r = lane & 15, koff = (lane >> 4) << 3;
        if (bid < 80){
          if (t < TO - 1){  // att A for step t+1: x / ac parts
            const int m = bid / 40, idx = bid % 40;
            const int ks = (idx < 8) ? idx : idx + 18;       // skip ctx 8..25
            const int row = m*16 + r;
            const int k = ks*32 + koff;
            bf8_t v = (k < PR)
              ? packrow(p.X2 + ((size_t)(t+1)*NB + row)*PR + k)
              : packrow_coh(p.AC + (size_t)row*AR + (k - PR - ED));
            cst_bf8(p.ABA + ((size_t)(m*NKT_A + ks)*64 + lane)*8, v);
          }
        } else {            // dec A for this step: ac / dh parts
          const int j2 = bid - 80;
          const int m = j2 / 64, idx = j2 % 64;
          const int ks = (idx < 32) ? idx : idx + 18;        // skip ctx 32..49
          const int row = m*16 + r;
          const int k = ks*32 + koff;
          bf8_t v = (k < AR)
            ? packrow_coh(p.AC + (size_t)row*AR + k)
            : packrow_coh(p.DH + (size_t)row*DR + (k - AR - ED));
          cst_bf8(p.ABD + ((size_t)(m*NKT_D + ks)*64 + lane)*8, v);
        }
      }
      __syncthreads();
      // energies: per-wave 16-d slice; loc-proj MFMA recomputed from sCwB.
      // PMEM is bf16; all 16 loads batched ahead of the tanh/shfl chain.
      const int b = bid >> 3, tc = bid & 7, t0 = tc*64;
      short* sCwB = (short*)(scr + SCR_CWB);
      float* eP = scr;                                 // [8][64]
      const int g = lane >> 4, li = lane & 15;
      const int d2 = wv*16 + li;
      const float vw = p.vW[d2];
      const float qd = sQ[d2];
      const bf8_t bfr = *(const bf8_t*)(p.WLOC + (size_t)(wv*64 + lane)*8);
      float pm[16];
      #pragma unroll
      for (int mt = 0; mt < 4; ++mt){
        #pragma unroll
        for (int r = 0; r < 4; ++r)
          pm[mt*4 + r] = bf2f(p.PMEMH[((size_t)b*TI + t0 + mt*16 + g*4 + r)*AD + d2]);
      }
      #pragma unroll
      for (int mt = 0; mt < 4; ++mt){
        const bf8_t afr = *(const bf8_t*)(sCwB + (mt*16 + li)*32 + (g << 3));
        f4_t c = (f4_t){0.f,0.f,0.f,0.f};
        c = MFMA(afr, bfr, c);
        #pragma unroll
        for (int r = 0; r < 4; ++r){
          const float val = c[r] + pm[mt*4 + r];
          float v = vw * tanhf(qd + val);
          v += __shfl_xor(v, 1);
          v += __shfl_xor(v, 2);
          v += __shfl_xor(v, 4);
          v += __shfl_xor(v, 8);
          if (li == 0) eP[wv*64 + mt*16 + g*4 + r] = v;
        }
      }
      __syncthreads();
      if (tid < 64){
        float e = eP[tid];
        #pragma unroll
        for (int w2 = 1; w2 < 8; ++w2) e += eP[w2*64 + tid];
        const int tg = t0 + tid;
        cst(&p.EN[b*TI + tg], (tg < p.mlen[b]) ? e : -1e30f);
      }
    }
    sibbar(mf, bid, tid, (unsigned)(t + 1));    // only EN crosses C|D

    // ------- PHASE D: softmax (shfl) + context ------------------------------
    {
      const int b = bid >> 3, ec = bid & 7;
      float* red = scr;                          // 8 floats
      float* sp  = scr + 64;                     // 512 floats
      const float e = cld(&p.EN[b*TI + tid]);
      float m = e;
      #pragma unroll
      for (int d = 32; d > 0; d >>= 1) m = fmaxf(m, __shfl_xor(m, d));
      if (lane == 0) red[wv] = m;
      __syncthreads();
      const float M = fmaxf(fmaxf(fmaxf(red[0], red[1]), fmaxf(red[2], red[3])),
                            fmaxf(fmaxf(red[4], red[5]), fmaxf(red[6], red[7])));
      const float x = __expf(e - M);
      float z = x;
      #pragma unroll
      for (int d = 32; d > 0; d >>= 1) z += __shfl_xor(z, d);
      __syncthreads();
      if (lane == 0) red[wv] = z;
      __syncthreads();
      const float Z = red[0]+red[1]+red[2]+red[3]+red[4]+red[5]+red[6]+red[7];
      const float pv = x / Z;
      sp[tid] = pv;
      __syncthreads();
      if (ec == 0){
        cst(&p.AW [(size_t)wp*NB*TI + b*TI + tid], pv);
        cst(&p.AWC[(size_t)wp*NB*TI + b*TI + tid],
            cld(&p.AWC[(size_t)rp*NB*TI + b*TI + tid]) + pv);
        p.out_align[((size_t)b*TO + t)*TI + tid] = pv;
      }
      // ctx: transposed bf16 memory; one bf8 load/lane/row (reordered dot)
      #pragma unroll
      for (int ii = 0; ii < 9; ++ii){
        const int e2 = ec*72 + wv*9 + ii;
        const short* row = p.MEMBT + ((size_t)b*ED + e2)*TI;
        const bf8_t w8 = *(const bf8_t*)(row + lane*8);
        const float* v = sp + lane*8;
        float a2 = v[0]*bf2f(w8[0]) + v[1]*bf2f(w8[1]) + v[2]*bf2f(w8[2]) + v[3]*bf2f(w8[3])
                 + v[4]*bf2f(w8[4]) + v[5]*bf2f(w8[5]) + v[6]*bf2f(w8[6]) + v[7]*bf2f(w8[7]);
        #pragma unroll
        for (int d = 32; d > 0; d >>= 1) a2 += __shfl_down(a2, d);
        if (lane == 0)
          cst(&p.CTX[(size_t)wp*NB*ED + b*ED + e2], a2);
      }
    }
    gbar(p.FLAGS, base + 3);
  }

  // ---- tail: dec-gates+cell(TO-1), then mel-proj(TO-1) ---------------------
  dec_gates_cell(p, sWD, scr, sDCc, (TO - 1) & 1, bid, lane, wv, tid);
  gbar(p.FLAGS, (unsigned)(TO*3 + 1));
  if (bid >= 224) dec_proj(p, bid - 224, TO - 1, tid, scr);
}

// ============================ setup kernels =================================
__global__ __launch_bounds__(256) void k_init(float* z, int nz,
                                              float* bsa, const float* a1, const float* a2,
                                              float* bsd, const float* d1, const float* d2){
  const int idx = blockIdx.x*256 + threadIdx.x, st = gridDim.x*256;
  const int NG = 4096;
  for (int i = idx; i < nz; i += st) z[i] = 0.f;
  for (int i = idx; i < NG; i += st){ bsa[i] = a1[i] + a2[i]; bsd[i] = d1[i] + d2[i]; }
}

__global__ __launch_bounds__(256) void k_prenet1(const float* di, const float* W1, float* X1){
  const int t = blockIdx.x, tid = threadIdx.x;
  __shared__ float sdi[NB*NM];
  for (int i = tid; i < NB*NM; i += 256){
    const int b = i / NM, k = i - b*NM;
    sdi[i] = (t == 0) ? 0.f : di[((size_t)b*TO + (t-1))*NM + k];
  }
  __syncthreads();
  float acc[NB];
  #pragma unroll
  for (int b = 0; b < NB; ++b) acc[b] = 0.f;
  const int j = tid;
  for (int k = 0; k < NM; ++k){
    const float w = W1[j*NM + k];
    #pragma unroll
    for (int b = 0; b < NB; ++b) acc[b] += sdi[b*NM + k] * w;
  }
  for (int b = 0; b < NB; ++b)
    X1[((size_t)t*NB + b)*PR + j] = fmaxf(acc[b], 0.f);
}

__global__ __launch_bounds__(256) void k_prenet2(const float* X1, const float* W2, float* X2){
  const int t = blockIdx.x, tid = threadIdx.x;
  __shared__ float sx[NB*PR];
  for (int i = tid; i < NB*PR; i += 256) sx[i] = X1[(size_t)t*NB*PR + i];
  __syncthreads();
  float acc[NB];
  #pragma unroll
  for (int b = 0; b < NB; ++b) acc[b] = 0.f;
  const int j = tid;
  for (int k = 0; k < PR; ++k){
    const float w = W2[j*PR + k];
    #pragma unroll
    for (int b = 0; b < NB; ++b) acc[b] += sx[b*PR + k] * w;
  }
  for (int b = 0; b < NB; ++b)
    X2[((size_t)t*NB + b)*PR + j] = fmaxf(acc[b], 0.f);
}

// pmem = memory @ memW.T -> bf16
__global__ __launch_bounds__(256) void k_pmem(const float* mem, const float* memW, short* pm){
  const int b = blockIdx.x >> 3, tc = blockIdx.x & 7, tid = threadIdx.x;
  __shared__ float sW[64*AD];
  __shared__ float sM[64*65];
  const int tl = tid >> 2, dq = tid & 3;
  float acc[32];
  #pragma unroll
  for (int i = 0; i < 32; ++i) acc[i] = 0.f;
  for (int kc = 0; kc < 9; ++kc){
    __syncthreads();
    for (int i = tid; i < 64*AD; i += 256){
      const int d = i >> 6, kl = i & 63;
      sW[kl*AD + ((d + kl) & 127)] = memW[(size_t)d*ED + kc*64 + kl];
    }
    for (int i = tid; i < 64*64; i += 256){
      const int tt = i >> 6, kl = i & 63;
      sM[tt*65 + kl] = mem[((size_t)b*TI + tc*64 + tt)*ED + kc*64 + kl];
    }
    __syncthreads();
    for (int kl = 0; kl < 64; ++kl){
      const float mv = sM[tl*65 + kl];
      #pragma unroll
      for (int d2 = 0; d2 < 32; ++d2)
        acc[d2] += mv * sW[kl*AD + ((dq*32 + d2 + kl) & 127)];
    }
  }
  for (int d2 = 0; d2 < 32; ++d2)
    pm[((size_t)b*TI + tc*64 + tl)*AD + dq*32 + d2] = f2bf(acc[d2]);
}

// memory -> bf16 transposed [b][e][t] (coalesced ctx matvec)
__global__ __launch_bounds__(256) void k_membt(const float* mem, short* mt){
  const int b = blockIdx.x / 36, ec = blockIdx.x % 36;
  __shared__ float sT[64*17];
  for (int tc = 0; tc < 8; ++tc){
    __syncthreads();
    for (int i = threadIdx.x; i < 64*16; i += 256){
      const int tt = i >> 4, e = i & 15;
      sT[tt*17 + e] = mem[((size_t)b*TI + tc*64 + tt)*ED + ec*16 + e];
    }
    __syncthreads();
    for (int i = threadIdx.x; i < 16*64; i += 256){
      const int e = i >> 6, tt = i & 63;
      mt[((size_t)b*ED + ec*16 + e)*TI + tc*64 + tt] = f2bf(sT[tt*17 + e]);
    }
  }
}

// weights -> bf16 MFMA B-fragment layout, gate-interleaved columns:
// tile nt, col nl: unit u = nt*4 + (nl>>2), gate gi = nl&3, row = gi*1024 + u
__global__ __launch_bounds__(64) void k_swz_gate(const float* Wih, const float* Whh,
                                                 short* dst, int split, int nkt){
  const int bidx = blockIdx.x;
  const int nt = bidx / nkt, kt = bidx - nt*nkt;
  const int lane = threadIdx.x;
  const int nl = lane & 15;
  const int jp = (nl & 3)*1024 + nt*4 + (nl >> 2);
  const int k0 = kt*32 + ((lane >> 4) << 3);
  bf8_t v;
  #pragma unroll
  for (int jj = 0; jj < 8; ++jj){
    const int k = k0 + jj;
    const float f = (k < split) ? Wih[(size_t)jp*split + k]
                                : Whh[(size_t)jp*1024 + (k - split)];
    v[jj] = f2bf(f);
  }
  *(bf8_t*)(dst + (size_t)bidx*512 + lane*8) = v;
}

__global__ __launch_bounds__(64) void k_swz_q(const float* qW, short* dst){
  const int bidx = blockIdx.x;                 // nt*32 + kt
  const int nt = bidx >> 5, kt = bidx & 31;
  const int lane = threadIdx.x;
  const int d = nt*16 + (lane & 15);
  const int k0 = kt*32 + ((lane >> 4) << 3);
  bf8_t v;
  #pragma unroll
  for (int jj = 0; jj < 8; ++jj) v[jj] = f2bf(qW[(size_t)d*AR + k0 + jj]);
  *(bf8_t*)(dst + (size_t)bidx*512 + lane*8) = v;
}

__global__ __launch_bounds__(64) void k_swz_loc(const float* locW, short* dst){
  const int nt = blockIdx.x;                   // 0..7
  const int lane = threadIdx.x;
  const int d = nt*16 + (lane & 15);
  const int f0 = (lane >> 4) << 3;
  bf8_t v;
  #pragma unroll
  for (int jj = 0; jj < 8; ++jj) v[jj] = f2bf(locW[d*NFl + f0 + jj]);
  *(bf8_t*)(dst + (size_t)(nt*64 + lane)*8) = v;
}

// projW(80x1600) + gateW(1x1600) -> bf16 rows, padded to stride 2048 (zeros)
__global__ __launch_bounds__(256) void k_swz_proj(const float* projW, const float* gateW,
                                                  short* dst){
  const int o = blockIdx.x;                    // 0..80
  const float* src = (o < 80) ? (projW + (size_t)o*1600) : gateW;
  for (int k = threadIdx.x; k < 2048; k += 256)
    dst[(size_t)o*2048 + k] = (k < 1600) ? f2bf(src[k]) : (short)0;
}

// ============================== launch ======================================
extern "C" void kernel_launch(void* const* d_in, const int* in_sizes, int n_in,
                              void* d_out, int out_size, void* d_ws, size_t ws_size,
                              hipStream_t stream){
  const float* mem    = (const float*)d_in[0];
  const float* dec_in = (const float*)d_in[1];
  const float* pW1    = (const float*)d_in[2];
  const float* pW2    = (const float*)d_in[3];
  const float* aWih   = (const float*)d_in[4];
  const float* aWhh   = (const float*)d_in[5];
  const float* aBih   = (const float*)d_in[6];
  const float* aBhh   = (const float*)d_in[7];
  const float* qW     = (const float*)d_in[8];
  const float* memW   = (const float*)d_in[9];
  const float* convW  = (const float*)d_in[10];
  const float* convb  = (const float*)d_in[11];
  const float* locW   = (const float*)d_in[12];
  const float* vW     = (const float*)d_in[13];
  const float* dWih   = (const float*)d_in[14];
  const float* dWhh   = (const float*)d_in[15];
  const float* dBih   = (const float*)d_in[16];
  const float* dBhh   = (const float*)d_in[17];
  const float* projW  = (const float*)d_in[18];
  const float* projb  = (const float*)d_in[19];
  const float* gateW  = (const float*)d_in[20];
  const float* gateb  = (const float*)d_in[21];
  const int*   mlen   = (const int*)d_in[22];
  (void)in_sizes; (void)n_in; (void)out_size; (void)ws_size;

  char* basep = (char*)d_ws;
  size_t off = 0;
  auto carve = [&](size_t bytes) -> char* {
    char* r = basep + off;
    off = (off + bytes + 255) & ~(size_t)255;
    return r;
  };
  const int NG = 4096;
  short* WA    = (short*)carve((size_t)NG*KA*2);
  short* WD    = (short*)carve((size_t)NG*KD*2);
  short* WQ    = (short*)carve((size_t)AD*AR*2);
  short* WLOC  = (short*)carve((size_t)AD*NFl*2);
  short* MEMBT = (short*)carve((size_t)NB*TI*ED*2);
  short* PJW   = (short*)carve((size_t)81*2048*2);
  short* PMEMH = (short*)carve((size_t)NB*TI*AD*2);
  float* X1    = (float*)carve((size_t)TO*NB*PR*4);
  float* X2    = (float*)carve((size_t)TO*NB*PR*4);
  float* BSA   = (float*)carve((size_t)NG*4);
  float* BSD   = (float*)carve((size_t)NG*4);
  short* ABA   = (short*)carve((size_t)2*NKT_A*512*2);
  short* ABD   = (short*)carve((size_t)2*NKT_D*512*2);
  // ---- zero-span begins here (contiguous through FLAGS) ----
  float* AC    = (float*)carve((size_t)NB*AR*4);
  float* DH    = (float*)carve((size_t)NB*DR*4);
  float* CTX   = (float*)carve((size_t)2*NB*ED*4);
  float* AW    = (float*)carve((size_t)2*NB*TI*4);
  float* AWC   = (float*)carve((size_t)2*NB*TI*4);
  float* EN    = (float*)carve((size_t)NB*TI*4);
  float* QP    = (float*)carve((size_t)4*NB*AD*4);
  unsigned* FLAGS = (unsigned*)carve((size_t)(MF_OFF + 256*FPAD)*4);
  const int nz = (int)((((char*)FLAGS + (size_t)(MF_OFF + 256*FPAD)*4) - (char*)AC) / 4);

  float* out_mel   = (float*)d_out;
  float* out_gate  = out_mel + (size_t)NB*NM*TO;
  float* out_align = out_gate + (size_t)NB*TO;

  k_init   <<<dim3(512), dim3(256), 0, stream>>>(AC, nz, BSA, aBih, aBhh, BSD, dBih, dBhh);
  k_prenet1<<<dim3(TO),  dim3(256), 0, stream>>>(dec_in, pW1, X1);
  k_prenet2<<<dim3(TO),  dim3(256), 0, stream>>>(X1, pW2, X2);
  k_pmem   <<<dim3(256), dim3(256), 0, stream>>>(mem, memW, PMEMH);
  k_membt  <<<dim3(NB*36), dim3(256), 0, stream>>>(mem, MEMBT);
  k_swz_gate<<<dim3(256*NKT_A), dim3(64), 0, stream>>>(aWih, aWhh, WA, 832, NKT_A);
  k_swz_gate<<<dim3(256*NKT_D), dim3(64), 0, stream>>>(dWih, dWhh, WD, 1600, NKT_D);
  k_swz_q  <<<dim3(256), dim3(64), 0, stream>>>(qW, WQ);
  k_swz_loc<<<dim3(8),   dim3(64), 0, stream>>>(locW, WLOC);
  k_swz_proj<<<dim3(81), dim3(256), 0, stream>>>(projW, gateW, PJW);

  Par p;
  p.X2 = X2; p.PMEMH = PMEMH;
  p.WA = WA; p.WD = WD; p.WQ = WQ; p.WLOC = WLOC; p.MEMBT = MEMBT; p.PJW = PJW;
  p.BSA = BSA; p.BSD = BSD;
  p.convW = convW; p.convb = convb; p.vW = vW;
  p.projb = projb; p.gateb = gateb;
  p.mlen = mlen;
  p.AC = AC; p.DH = DH; p.CTX = CTX;
  p.AW = AW; p.AWC = AWC; p.EN = EN; p.QP = QP;
  p.ABA = ABA; p.ABD = ABD;
  p.out_mel = out_mel; p.out_gate = out_gate; p.out_align = out_align;
  p.FLAGS = FLAGS;

  (void)hipFuncSetAttribute((const void*)k_loop,
                            hipFuncAttributeMaxDynamicSharedMemorySize, LDS_TOTAL);
  k_loop<<<dim3(256), dim3(512), LDS_TOTAL, stream>>>(p);
}